// Round 3
// baseline (428.073 us; speedup 1.0000x reference)
//
#include <hip/hip_runtime.h>
#include <hip/hip_fp16.h>
#include <stdint.h>
#include <stddef.h>

#define N_NODES 100000
#define N_EDGES 6400000
#define HIDDEN 16
#define NBKT 782          /* ceil(100000/128) coarse buckets of 128 nodes */
#define CAP 8704          /* bucket region capacity: mean 8184 + 5.7 sigma */
#define P1_EPB 8192       /* edges per part1 block */
#define NMASK 1600000     /* N_NODES*HIDDEN */

__host__ __device__ inline uint32_t rotl32(uint32_t x, int n) {
    return (x << n) | (x >> (32 - n));
}

// Exact JAX threefry2x32 (20 rounds)
__host__ __device__ inline void threefry2x32(uint32_t k0, uint32_t k1,
                                             uint32_t x0, uint32_t x1,
                                             uint32_t& o0, uint32_t& o1) {
    uint32_t k2 = k0 ^ k1 ^ 0x1BD11BDAu;
    x0 += k0; x1 += k1;
    x0 += x1; x1 = rotl32(x1, 13); x1 ^= x0;
    x0 += x1; x1 = rotl32(x1, 15); x1 ^= x0;
    x0 += x1; x1 = rotl32(x1, 26); x1 ^= x0;
    x0 += x1; x1 = rotl32(x1,  6); x1 ^= x0;
    x0 += k1; x1 += k2 + 1u;
    x0 += x1; x1 = rotl32(x1, 17); x1 ^= x0;
    x0 += x1; x1 = rotl32(x1, 29); x1 ^= x0;
    x0 += x1; x1 = rotl32(x1, 16); x1 ^= x0;
    x0 += x1; x1 = rotl32(x1, 24); x1 ^= x0;
    x0 += k2; x1 += k0 + 2u;
    x0 += x1; x1 = rotl32(x1, 13); x1 ^= x0;
    x0 += x1; x1 = rotl32(x1, 15); x1 ^= x0;
    x0 += x1; x1 = rotl32(x1, 26); x1 ^= x0;
    x0 += x1; x1 = rotl32(x1,  6); x1 ^= x0;
    x0 += k0; x1 += k1 + 3u;
    x0 += x1; x1 = rotl32(x1, 17); x1 ^= x0;
    x0 += x1; x1 = rotl32(x1, 29); x1 ^= x0;
    x0 += x1; x1 = rotl32(x1, 16); x1 ^= x0;
    x0 += x1; x1 = rotl32(x1, 24); x1 ^= x0;
    x0 += k1; x1 += k2 + 4u;
    x0 += x1; x1 = rotl32(x1, 13); x1 ^= x0;
    x0 += x1; x1 = rotl32(x1, 15); x1 ^= x0;
    x0 += x1; x1 = rotl32(x1, 26); x1 ^= x0;
    x0 += x1; x1 = rotl32(x1,  6); x1 ^= x0;
    x0 += k2; x1 += k0 + 5u;
    o0 = x0; o1 = x1;
}

// ---- fp16 row helpers (gather tables are fp16; accumulation is fp32) -----
__device__ inline float4 ldh4(const __half* p) {
    uint2 u = *(const uint2*)p;                 // 8B aligned load
    __half2 h0 = *(__half2*)&u.x;
    __half2 h1 = *(__half2*)&u.y;
    float2 a = __half22float2(h0), b = __half22float2(h1);
    return make_float4(a.x, a.y, b.x, b.y);
}
__device__ inline void sth4(__half* p, float4 v) {
    __half2 h0 = __floats2half2_rn(v.x, v.y);
    __half2 h1 = __floats2half2_rn(v.z, v.w);
    uint2 u;
    u.x = *(uint32_t*)&h0; u.y = *(uint32_t*)&h1;
    *(uint2*)p = u;
}

// ---- dropout keep-bit masks, 1 threefry eval per lane, ballot-packed -----
__global__ __launch_bounds__(256) void dropmask_kernel(uint64_t* __restrict__ m1,
                                                       uint64_t* __restrict__ m2,
                                                       uint32_t k10, uint32_t k11,
                                                       uint32_t k20, uint32_t k21) {
    int g = blockIdx.x * blockDim.x + threadIdx.x;   // [0, 2*NMASK)
    int lane = threadIdx.x & 63;
    bool first = g < NMASK;
    uint32_t j = first ? (uint32_t)g : (uint32_t)(g - NMASK);
    uint32_t a, b;
    threefry2x32(first ? k10 : k20, first ? k11 : k21, 0u, j, a, b);
    uint32_t bits = a ^ b;
    float u = __uint_as_float((bits >> 9) | 0x3F800000u) - 1.0f;
    unsigned long long m = __ballot(u >= 0.3f);
    if (lane == 0) {
        int gw = g >> 6;
        if (first) m1[gw] = m;
        else       m2[gw - (NMASK >> 6)] = m;
    }
}

// ---- gcursor[b] = b*CAP (fixed-capacity bucket regions, no scan) ---------
__global__ void initcur_kernel(int* __restrict__ gcursor) {
    int b = threadIdx.x;
    if (b < NBKT) gcursor[b] = b * CAP;
}

// ---- partition pass 1: coarse counting sort, direct global scatter -------
// Per block: LDS histogram of its 8192 edges -> one global atomicAdd per
// non-empty bucket (reserves a contiguous run in buf) -> second pass writes
// each edge to buf[lbase[b] + local_rank]. No scan, no staging, 3 barriers.
// A block's writes to one bucket are a contiguous ~42B run (same pattern
// the old lsort+flush produced, without the 32KB LDS + 18-barrier scan).
__global__ __launch_bounds__(512) void part1_kernel(const int* __restrict__ src,
                                                    const int* __restrict__ dst,
                                                    int* __restrict__ gcursor,
                                                    int* __restrict__ buf) {
    __shared__ int lhist[NBKT], lbase[NBKT], lcur[NBKT];
    int tid = threadIdx.x;
    size_t base = (size_t)blockIdx.x * P1_EPB;
    for (int b = tid; b < NBKT; b += 512) lhist[b] = 0;
    __syncthreads();
    #pragma unroll
    for (int i = 0; i < 16; i++) {
        size_t e = base + (size_t)i * 512 + tid;
        if (e < N_EDGES) atomicAdd(&lhist[dst[e] >> 7], 1);
    }
    __syncthreads();
    for (int b = tid; b < NBKT; b += 512) {
        int c = lhist[b];
        lbase[b] = c ? atomicAdd(&gcursor[b], c) : 0;
        lcur[b] = 0;
    }
    __syncthreads();
    #pragma unroll
    for (int i = 0; i < 16; i++) {
        size_t e = base + (size_t)i * 512 + tid;
        if (e < N_EDGES) {
            int d = dst[e], s = src[e];
            int b = d >> 7;
            int r = atomicAdd(&lcur[b], 1);
            int pos = lbase[b] + r;
            if (pos < (b + 1) * CAP)   // capacity guard (P ~ 5e-6 total)
                buf[pos] = ((d & 127) << 17) | s;
        }
    }
}

// ---- part2: per-bucket fine sort in LDS, in place; emits nodeinfo+dinv ---
__global__ __launch_bounds__(512) void part2_kernel(const int* __restrict__ gcursor,
                                                    int* __restrict__ buf,
                                                    int* __restrict__ nodeinfo,
                                                    float* __restrict__ dinv) {
    __shared__ int lcnt[128], lcur[128];
    __shared__ int lsort[CAP];
    int b = blockIdx.x, tid = threadIdx.x;
    int base = b * CAP;
    int end = gcursor[b];
    int count = end - base;
    if (tid < 128) lcnt[tid] = 0;
    __syncthreads();
    for (int i = tid; i < count; i += 512)
        atomicAdd(&lcnt[buf[base + i] >> 17], 1);
    __syncthreads();
    int v = (tid < 128) ? lcnt[tid] : 0;
    #pragma unroll
    for (int o = 1; o < 128; o <<= 1) {
        int t2 = (tid < 128 && tid >= o) ? lcnt[tid - o] : 0;
        __syncthreads();
        if (tid < 128 && tid >= o) lcnt[tid] += t2;
        __syncthreads();
    }
    if (tid < 128) {
        int excl = lcnt[tid] - v;
        lcur[tid] = excl;
        int n = b * 128 + tid;
        if (n < N_NODES) {
            nodeinfo[n] = (v << 23) | (base + excl);
            dinv[n] = rsqrtf((float)v + 1.0f);  // +1 self-loop
        }
    }
    __syncthreads();
    for (int i = tid; i < count; i += 512) {
        int w = buf[base + i];
        int pos = atomicAdd(&lcur[w >> 17], 1);
        lsort[pos] = w & 0x1FFFF;
    }
    __syncthreads();
    for (int i = tid; i < count; i += 512) buf[base + i] = lsort[i];
}

// ---- LayerNorm + W1 + pre-scale by dinv (one wave per node) --------------
// Emits g1 in fp16: 32B/row -> 3.2MB table, fits one XCD's 4MB L2.
__global__ void ln_w1_kernel(const float* __restrict__ x,
                             const float* __restrict__ gamma,
                             const float* __restrict__ beta,
                             const float* __restrict__ W1,
                             const float* __restrict__ dinv,
                             __half* __restrict__ g1) {
    int wave = (blockIdx.x * blockDim.x + threadIdx.x) >> 6;
    int lane = threadIdx.x & 63;
    if (wave >= N_NODES) return;
    const float* xr = x + (size_t)wave * 128;
    float x0 = xr[lane], x1 = xr[lane + 64];

    float s1 = x0 + x1;
    float s2 = x0 * x0 + x1 * x1;
    #pragma unroll
    for (int o = 32; o; o >>= 1) {
        s1 += __shfl_xor(s1, o, 64);
        s2 += __shfl_xor(s2, o, 64);
    }
    float mu = s1 * (1.0f / 128.0f);
    float var = s2 * (1.0f / 128.0f) - mu * mu;
    float rstd = rsqrtf(var + 1e-5f);
    float xn0 = (x0 - mu) * rstd * gamma[lane] + beta[lane];
    float xn1 = (x1 - mu) * rstd * gamma[lane + 64] + beta[lane + 64];

    float p[16];
    const float* wr0 = W1 + (size_t)lane * HIDDEN;
    const float* wr1 = W1 + (size_t)(lane + 64) * HIDDEN;
    #pragma unroll
    for (int j = 0; j < 16; j++) p[j] = xn0 * wr0[j] + xn1 * wr1[j];

    // vector-halving butterfly
    float q[8];
    {
        int sel = lane & 1;
        #pragma unroll
        for (int j = 0; j < 8; j++) {
            float mine = sel ? p[j + 8] : p[j];
            float give = sel ? p[j] : p[j + 8];
            q[j] = mine + __shfl_xor(give, 1, 64);
        }
    }
    float r[4];
    {
        int sel = (lane >> 1) & 1;
        #pragma unroll
        for (int j = 0; j < 4; j++) {
            float mine = sel ? q[j + 4] : q[j];
            float give = sel ? q[j] : q[j + 4];
            r[j] = mine + __shfl_xor(give, 2, 64);
        }
    }
    float s[2];
    {
        int sel = (lane >> 2) & 1;
        #pragma unroll
        for (int j = 0; j < 2; j++) {
            float mine = sel ? r[j + 2] : r[j];
            float give = sel ? r[j] : r[j + 2];
            s[j] = mine + __shfl_xor(give, 4, 64);
        }
    }
    float t;
    {
        int sel = (lane >> 3) & 1;
        float mine = sel ? s[1] : s[0];
        float give = sel ? s[0] : s[1];
        t = mine + __shfl_xor(give, 8, 64);
    }
    t += __shfl_xor(t, 16, 64);
    t += __shfl_xor(t, 32, 64);

    if (lane < 16) {
        int f = ((lane & 1) << 3) | ((lane & 2) << 1) |
                ((lane & 4) >> 1) | ((lane & 8) >> 3);  // bitrev4
        g1[(size_t)wave * HIDDEN + f] = __float2half_rn(t * dinv[wave]);
    }
}

// ---- pull conv1 + fused finalize1: 4 nodes per wave, fp16 gather ---------
__global__ __launch_bounds__(256) void pull1_kernel(const int* __restrict__ nodeinfo,
                             const int* __restrict__ sorted_src,
                             const __half* __restrict__ g1,
                             const float* __restrict__ dinv,
                             const float* __restrict__ b1,
                             const float* __restrict__ W2,
                             const uint64_t* __restrict__ m1,
                             __half* __restrict__ g2) {
    __shared__ float sW2[HIDDEN * HIDDEN];
    if (threadIdx.x < HIDDEN * HIDDEN) sW2[threadIdx.x] = W2[threadIdx.x];
    __syncthreads();
    int n = blockIdx.x * 16 + (threadIdx.x >> 4);  // grid*16 == N_NODES
    int l = threadIdx.x & 15;
    int c = l & 3, e = l >> 2;
    uint32_t co = (uint32_t)(c * 4);
    int info = nodeinfo[n];
    int start = info & 0x7FFFFF;
    int deg = (int)((unsigned)info >> 23);

    float4 acc = make_float4(0.f, 0.f, 0.f, 0.f);
    float4 acc2 = make_float4(0.f, 0.f, 0.f, 0.f);
    if (e == 0) acc = ldh4(g1 + (uint32_t)n * HIDDEN + co);  // self
    int km = (deg > 0) ? deg - 1 : 0;
    int eb = e * 4;
    for (int kb = 0; kb < deg; kb += 16) {
        int k0 = kb + eb;
        // unconditional clamped idx loads: issue all 4 up front (MLP)
        int s0 = sorted_src[start + min(k0,     km)];
        int s1 = sorted_src[start + min(k0 + 1, km)];
        int s2 = sorted_src[start + min(k0 + 2, km)];
        int s3 = sorted_src[start + min(k0 + 3, km)];
        if (k0 < deg) {
            const float4 gv = ldh4(g1 + (uint32_t)s0 * HIDDEN + co);
            acc.x += gv.x; acc.y += gv.y; acc.z += gv.z; acc.w += gv.w;
        }
        if (k0 + 1 < deg) {
            const float4 gv = ldh4(g1 + (uint32_t)s1 * HIDDEN + co);
            acc2.x += gv.x; acc2.y += gv.y; acc2.z += gv.z; acc2.w += gv.w;
        }
        if (k0 + 2 < deg) {
            const float4 gv = ldh4(g1 + (uint32_t)s2 * HIDDEN + co);
            acc.x += gv.x; acc.y += gv.y; acc.z += gv.z; acc.w += gv.w;
        }
        if (k0 + 3 < deg) {
            const float4 gv = ldh4(g1 + (uint32_t)s3 * HIDDEN + co);
            acc2.x += gv.x; acc2.y += gv.y; acc2.z += gv.z; acc2.w += gv.w;
        }
    }
    acc.x += acc2.x; acc.y += acc2.y; acc.z += acc2.z; acc.w += acc2.w;
    // reduce over the 4 edge slots (stays within the 16-lane group)
    #pragma unroll
    for (int o = 4; o <= 8; o <<= 1) {
        acc.x += __shfl_xor(acc.x, o, 64);
        acc.y += __shfl_xor(acc.y, o, 64);
        acc.z += __shfl_xor(acc.z, o, 64);
        acc.w += __shfl_xor(acc.w, o, 64);
    }
    float di = dinv[n];
    const float4 b1c = *(const float4*)&b1[c * 4];
    uint32_t mbits = (uint32_t)(m1[n >> 2] >> ((n & 3) * 16));
    const float inv = 1.0f / 0.7f;
    float h[4];
    h[0] = ((mbits >> (c * 4 + 0)) & 1) ? fmaxf(di * acc.x + b1c.x, 0.f) * inv : 0.f;
    h[1] = ((mbits >> (c * 4 + 1)) & 1) ? fmaxf(di * acc.y + b1c.y, 0.f) * inv : 0.f;
    h[2] = ((mbits >> (c * 4 + 2)) & 1) ? fmaxf(di * acc.z + b1c.z, 0.f) * inv : 0.f;
    h[3] = ((mbits >> (c * 4 + 3)) & 1) ? fmaxf(di * acc.w + b1c.w, 0.f) * inv : 0.f;
    // h @ W2: broadcast h[i] from lanes 0..3 of this group (e==0, c=i>>2)
    int grpbase = threadIdx.x & 48;
    float4 o4 = make_float4(0.f, 0.f, 0.f, 0.f);
    #pragma unroll
    for (int i = 0; i < HIDDEN; i++) {
        float hi = __shfl(h[i & 3], grpbase + (i >> 2), 64);
        const float4 w = *(const float4*)&sW2[i * HIDDEN + c * 4];
        o4.x += hi * w.x; o4.y += hi * w.y; o4.z += hi * w.z; o4.w += hi * w.w;
    }
    if (e == 0)
        sth4(g2 + (uint32_t)n * HIDDEN + co,
             make_float4(o4.x * di, o4.y * di, o4.z * di, o4.w * di));
}

// ---- pull conv2 + fused finalize2: fp16 gather, fp32 output --------------
__global__ __launch_bounds__(256) void pull2_kernel(const int* __restrict__ nodeinfo,
                             const int* __restrict__ sorted_src,
                             const __half* __restrict__ g2,
                             const float* __restrict__ dinv,
                             const float* __restrict__ b2,
                             const uint64_t* __restrict__ m2,
                             float* __restrict__ out) {
    int n = blockIdx.x * 16 + (threadIdx.x >> 4);
    int l = threadIdx.x & 15;
    int c = l & 3, e = l >> 2;
    uint32_t co = (uint32_t)(c * 4);
    int info = nodeinfo[n];
    int start = info & 0x7FFFFF;
    int deg = (int)((unsigned)info >> 23);

    float4 acc = make_float4(0.f, 0.f, 0.f, 0.f);
    float4 acc2 = make_float4(0.f, 0.f, 0.f, 0.f);
    if (e == 0) acc = ldh4(g2 + (uint32_t)n * HIDDEN + co);  // self
    int km = (deg > 0) ? deg - 1 : 0;
    int eb = e * 4;
    for (int kb = 0; kb < deg; kb += 16) {
        int k0 = kb + eb;
        int s0 = sorted_src[start + min(k0,     km)];
        int s1 = sorted_src[start + min(k0 + 1, km)];
        int s2 = sorted_src[start + min(k0 + 2, km)];
        int s3 = sorted_src[start + min(k0 + 3, km)];
        if (k0 < deg) {
            const float4 gv = ldh4(g2 + (uint32_t)s0 * HIDDEN + co);
            acc.x += gv.x; acc.y += gv.y; acc.z += gv.z; acc.w += gv.w;
        }
        if (k0 + 1 < deg) {
            const float4 gv = ldh4(g2 + (uint32_t)s1 * HIDDEN + co);
            acc2.x += gv.x; acc2.y += gv.y; acc2.z += gv.z; acc2.w += gv.w;
        }
        if (k0 + 2 < deg) {
            const float4 gv = ldh4(g2 + (uint32_t)s2 * HIDDEN + co);
            acc.x += gv.x; acc.y += gv.y; acc.z += gv.z; acc.w += gv.w;
        }
        if (k0 + 3 < deg) {
            const float4 gv = ldh4(g2 + (uint32_t)s3 * HIDDEN + co);
            acc2.x += gv.x; acc2.y += gv.y; acc2.z += gv.z; acc2.w += gv.w;
        }
    }
    acc.x += acc2.x; acc.y += acc2.y; acc.z += acc2.z; acc.w += acc2.w;
    #pragma unroll
    for (int o = 4; o <= 8; o <<= 1) {
        acc.x += __shfl_xor(acc.x, o, 64);
        acc.y += __shfl_xor(acc.y, o, 64);
        acc.z += __shfl_xor(acc.z, o, 64);
        acc.w += __shfl_xor(acc.w, o, 64);
    }
    if (e == 0) {
        float di = dinv[n];
        const float4 b2c = *(const float4*)&b2[c * 4];
        uint32_t mbits = (uint32_t)(m2[n >> 2] >> ((n & 3) * 16));
        const float inv = 1.0f / 0.7f;
        float4 r;
        r.x = ((mbits >> (c * 4 + 0)) & 1) ? fmaxf(di * acc.x + b2c.x, 0.f) * inv : 0.f;
        r.y = ((mbits >> (c * 4 + 1)) & 1) ? fmaxf(di * acc.y + b2c.y, 0.f) * inv : 0.f;
        r.z = ((mbits >> (c * 4 + 2)) & 1) ? fmaxf(di * acc.z + b2c.z, 0.f) * inv : 0.f;
        r.w = ((mbits >> (c * 4 + 3)) & 1) ? fmaxf(di * acc.w + b2c.w, 0.f) * inv : 0.f;
        *(float4*)&out[(uint32_t)n * HIDDEN + co] = r;
    }
}

extern "C" void kernel_launch(void* const* d_in, const int* in_sizes, int n_in,
                              void* d_out, int out_size, void* d_ws, size_t ws_size,
                              hipStream_t stream) {
    const float* x     = (const float*)d_in[0];
    const int*   ei    = (const int*)d_in[1];
    const float* gamma = (const float*)d_in[2];
    const float* beta  = (const float*)d_in[3];
    const float* W1    = (const float*)d_in[4];
    const float* b1    = (const float*)d_in[5];
    const float* W2    = (const float*)d_in[6];
    const float* b2    = (const float*)d_in[7];
    float* out = (float*)d_out;
    const int* src = ei;
    const int* dst = ei + N_EDGES;

    uint32_t dk1_0, dk1_1, dk2_0, dk2_1;
    threefry2x32(0u, 42u, 0u, 0u, dk1_0, dk1_1);
    threefry2x32(0u, 42u, 0u, 1u, dk2_0, dk2_1);

    // ws layout (4B elems): gcursor[1024] | nodeinfo[100k] | dinv[100k] |
    // buf[NBKT*CAP] | g1h[1.6M half = 800k int] | g2h[800k int] |
    // m1[25k ull] | m2[25k ull]  (~36MB)
    int*      gcursor  = (int*)d_ws;
    int*      nodeinfo = gcursor + 1024;
    float*    dinv     = (float*)(nodeinfo + N_NODES);
    int*      buf      = (int*)(dinv + N_NODES);
    __half*   g1h      = (__half*)(buf + (size_t)NBKT * CAP);
    __half*   g2h      = g1h + (size_t)N_NODES * HIDDEN;
    uint64_t* m1       = (uint64_t*)(g2h + (size_t)N_NODES * HIDDEN);
    uint64_t* m2       = m1 + (NMASK >> 6);

    const int NB_W  = N_NODES / 4;                     // 25000 (ln_w1: 4 waves/block)
    const int NB_PULL = N_NODES / 16;                  // 6250 (pull: 16 nodes/block)
    const int NB_P1 = (N_EDGES + P1_EPB - 1) / P1_EPB; // 782

    initcur_kernel<<<1, 1024, 0, stream>>>(gcursor);
    dropmask_kernel<<<(2 * NMASK) / 256, 256, 0, stream>>>(m1, m2,
                                                           dk1_0, dk1_1,
                                                           dk2_0, dk2_1);
    part1_kernel<<<NB_P1, 512, 0, stream>>>(src, dst, gcursor, buf);
    part2_kernel<<<NBKT, 512, 0, stream>>>(gcursor, buf, nodeinfo, dinv);
    ln_w1_kernel<<<NB_W, 256, 0, stream>>>(x, gamma, beta, W1, dinv, g1h);
    pull1_kernel<<<NB_PULL, 256, 0, stream>>>(nodeinfo, buf, g1h,
                                              dinv, b1, W2, m1, g2h);
    pull2_kernel<<<NB_PULL, 256, 0, stream>>>(nodeinfo, buf, g2h,
                                              dinv, b2, m2, out);
}

// Round 4
// 328.587 us; speedup vs baseline: 1.3028x; 1.3028x over previous
//
#include <hip/hip_runtime.h>
#include <hip/hip_fp16.h>
#include <stdint.h>
#include <stddef.h>

#define N_NODES 100000
#define N_EDGES 6400000
#define HIDDEN 16
#define NBKT 782          /* ceil(100000/128) coarse buckets of 128 nodes */
#define CAP 8704          /* bucket region capacity: mean 8184 + 5.7 sigma */
#define P1_EPB 8192       /* edges per part1 block */
#define NMASK 1600000     /* N_NODES*HIDDEN */

__host__ __device__ inline uint32_t rotl32(uint32_t x, int n) {
    return (x << n) | (x >> (32 - n));
}

// Exact JAX threefry2x32 (20 rounds)
__host__ __device__ inline void threefry2x32(uint32_t k0, uint32_t k1,
                                             uint32_t x0, uint32_t x1,
                                             uint32_t& o0, uint32_t& o1) {
    uint32_t k2 = k0 ^ k1 ^ 0x1BD11BDAu;
    x0 += k0; x1 += k1;
    x0 += x1; x1 = rotl32(x1, 13); x1 ^= x0;
    x0 += x1; x1 = rotl32(x1, 15); x1 ^= x0;
    x0 += x1; x1 = rotl32(x1, 26); x1 ^= x0;
    x0 += x1; x1 = rotl32(x1,  6); x1 ^= x0;
    x0 += k1; x1 += k2 + 1u;
    x0 += x1; x1 = rotl32(x1, 17); x1 ^= x0;
    x0 += x1; x1 = rotl32(x1, 29); x1 ^= x0;
    x0 += x1; x1 = rotl32(x1, 16); x1 ^= x0;
    x0 += x1; x1 = rotl32(x1, 24); x1 ^= x0;
    x0 += k2; x1 += k0 + 2u;
    x0 += x1; x1 = rotl32(x1, 13); x1 ^= x0;
    x0 += x1; x1 = rotl32(x1, 15); x1 ^= x0;
    x0 += x1; x1 = rotl32(x1, 26); x1 ^= x0;
    x0 += x1; x1 = rotl32(x1,  6); x1 ^= x0;
    x0 += k0; x1 += k1 + 3u;
    x0 += x1; x1 = rotl32(x1, 17); x1 ^= x0;
    x0 += x1; x1 = rotl32(x1, 29); x1 ^= x0;
    x0 += x1; x1 = rotl32(x1, 16); x1 ^= x0;
    x0 += x1; x1 = rotl32(x1, 24); x1 ^= x0;
    x0 += k1; x1 += k2 + 4u;
    x0 += x1; x1 = rotl32(x1, 13); x1 ^= x0;
    x0 += x1; x1 = rotl32(x1, 15); x1 ^= x0;
    x0 += x1; x1 = rotl32(x1, 26); x1 ^= x0;
    x0 += x1; x1 = rotl32(x1,  6); x1 ^= x0;
    x0 += k2; x1 += k0 + 5u;
    o0 = x0; o1 = x1;
}

// ---- fp16 row helpers (gather tables are fp16; accumulation is fp32) -----
__device__ inline float4 ldh4(const __half* p) {
    uint2 u = *(const uint2*)p;                 // 8B aligned load
    __half2 h0 = *(__half2*)&u.x;
    __half2 h1 = *(__half2*)&u.y;
    float2 a = __half22float2(h0), b = __half22float2(h1);
    return make_float4(a.x, a.y, b.x, b.y);
}
__device__ inline void sth4(__half* p, float4 v) {
    __half2 h0 = __floats2half2_rn(v.x, v.y);
    __half2 h1 = __floats2half2_rn(v.z, v.w);
    uint2 u;
    u.x = *(uint32_t*)&h0; u.y = *(uint32_t*)&h1;
    *(uint2*)p = u;
}

// ---- dropout keep-bit masks, 1 threefry eval per lane, ballot-packed -----
__global__ __launch_bounds__(256) void dropmask_kernel(uint64_t* __restrict__ m1,
                                                       uint64_t* __restrict__ m2,
                                                       uint32_t k10, uint32_t k11,
                                                       uint32_t k20, uint32_t k21) {
    int g = blockIdx.x * blockDim.x + threadIdx.x;   // [0, 2*NMASK)
    int lane = threadIdx.x & 63;
    bool first = g < NMASK;
    uint32_t j = first ? (uint32_t)g : (uint32_t)(g - NMASK);
    uint32_t a, b;
    threefry2x32(first ? k10 : k20, first ? k11 : k21, 0u, j, a, b);
    uint32_t bits = a ^ b;
    float u = __uint_as_float((bits >> 9) | 0x3F800000u) - 1.0f;
    unsigned long long m = __ballot(u >= 0.3f);
    if (lane == 0) {
        int gw = g >> 6;
        if (first) m1[gw] = m;
        else       m2[gw - (NMASK >> 6)] = m;
    }
}

// ---- gcursor[b] = b*CAP (fixed-capacity bucket regions, no scan) ---------
__global__ void initcur_kernel(int* __restrict__ gcursor) {
    int b = threadIdx.x;
    if (b < NBKT) gcursor[b] = b * CAP;
}

// ---- partition pass 1: LDS counting sort, int4 loads, shuffle scan -------
// hist -> wave-shuffle scan (5 barriers total) -> per-bucket global cursor
// reservation -> LDS lsort staging -> 16-lane-group coalesced run flush.
// lsort staging is load-bearing: it turns 6.4M scattered 4B stores into
// contiguous ~42B runs (R3 measured 172MB writes without it vs 43MB with).
__global__ __launch_bounds__(512) void part1_kernel(const int* __restrict__ src,
                                                    const int* __restrict__ dst,
                                                    int* __restrict__ gcursor,
                                                    int* __restrict__ buf) {
    __shared__ int lhist[NBKT], lbase[NBKT], lstart[NBKT], lcur[NBKT];
    __shared__ int wsum[8];
    __shared__ int lsort[P1_EPB];
    int tid = threadIdx.x;
    const int NV4 = N_EDGES >> 2;                 // 1.6M int4 groups
    int base4 = blockIdx.x * (P1_EPB >> 2);       // 2048 int4 per block
    const int4* dst4 = (const int4*)dst;
    const int4* src4 = (const int4*)src;

    for (int b = tid; b < NBKT; b += 512) lhist[b] = 0;
    __syncthreads();
    #pragma unroll
    for (int i = 0; i < 4; i++) {
        int e4 = base4 + i * 512 + tid;
        if (e4 < NV4) {
            int4 d = dst4[e4];
            atomicAdd(&lhist[d.x >> 7], 1);
            atomicAdd(&lhist[d.y >> 7], 1);
            atomicAdd(&lhist[d.z >> 7], 1);
            atomicAdd(&lhist[d.w >> 7], 1);
        }
    }
    __syncthreads();
    // exclusive scan over 782 bucket counts: thread t owns buckets 2t,2t+1
    int i0 = tid * 2, i1 = i0 + 1;
    int c0 = (i0 < NBKT) ? lhist[i0] : 0;
    int c1 = (i1 < NBKT) ? lhist[i1] : 0;
    int v = c0 + c1;
    int lane = tid & 63, wid = tid >> 6;
    int sc = v;
    #pragma unroll
    for (int o = 1; o < 64; o <<= 1) {
        int t2 = __shfl_up(sc, o, 64);
        if (lane >= o) sc += t2;
    }
    if (lane == 63) wsum[wid] = sc;
    __syncthreads();
    int wo = 0;
    #pragma unroll
    for (int w = 0; w < 8; w++) wo += (w < wid) ? wsum[w] : 0;
    int excl = sc - v + wo;
    if (i0 < NBKT) { lstart[i0] = excl;      lcur[i0] = excl; }
    if (i1 < NBKT) { lstart[i1] = excl + c0; lcur[i1] = excl + c0; }
    for (int b = tid; b < NBKT; b += 512) {
        int c = lhist[b];
        lbase[b] = c ? atomicAdd(&gcursor[b], c) : 0;
    }
    __syncthreads();
    #pragma unroll
    for (int i = 0; i < 4; i++) {
        int e4 = base4 + i * 512 + tid;
        if (e4 < NV4) {
            int4 d = dst4[e4];
            int4 s = src4[e4];
            int p0 = atomicAdd(&lcur[d.x >> 7], 1);
            lsort[p0] = ((d.x & 127) << 17) | s.x;
            int p1 = atomicAdd(&lcur[d.y >> 7], 1);
            lsort[p1] = ((d.y & 127) << 17) | s.y;
            int p2 = atomicAdd(&lcur[d.z >> 7], 1);
            lsort[p2] = ((d.z & 127) << 17) | s.z;
            int p3 = atomicAdd(&lcur[d.w >> 7], 1);
            lsort[p3] = ((d.w & 127) << 17) | s.w;
        }
    }
    __syncthreads();
    int grp = tid >> 4, gl = tid & 15;
    for (int b = grp; b < NBKT; b += 32) {
        int st = lstart[b], c = lhist[b], gb = lbase[b];
        int lim = (b + 1) * CAP;
        for (int k = gl; k < c; k += 16) {
            int pos = gb + k;
            if (pos < lim)   // capacity guard (P ~ 5e-6 total)
                buf[pos] = lsort[st + k];
        }
    }
}

// ---- part2: per-bucket fine sort in LDS; int4 loads, shuffle scan --------
__global__ __launch_bounds__(512) void part2_kernel(const int* __restrict__ gcursor,
                                                    int* __restrict__ buf,
                                                    int* __restrict__ nodeinfo,
                                                    float* __restrict__ dinv) {
    __shared__ int lcnt[128], lcur[128];
    __shared__ int w0sum;
    __shared__ int lsort[CAP];
    int b = blockIdx.x, tid = threadIdx.x;
    int base = b * CAP;                 // CAP%4==0 -> 16B aligned
    int end = gcursor[b];
    int count = end - base;
    int cnt4 = count >> 2;
    const int4* buf4 = (const int4*)(buf + base);
    if (tid < 128) lcnt[tid] = 0;
    __syncthreads();
    for (int i = tid; i < cnt4; i += 512) {
        int4 w = buf4[i];
        atomicAdd(&lcnt[w.x >> 17], 1);
        atomicAdd(&lcnt[w.y >> 17], 1);
        atomicAdd(&lcnt[w.z >> 17], 1);
        atomicAdd(&lcnt[w.w >> 17], 1);
    }
    for (int i = (cnt4 << 2) + tid; i < count; i += 512)
        atomicAdd(&lcnt[buf[base + i] >> 17], 1);
    __syncthreads();
    // shuffle scan over 128 counters (waves 0 and 1)
    if (tid < 128) {
        int v = lcnt[tid];
        int lane = tid & 63;
        int sc = v;
        #pragma unroll
        for (int o = 1; o < 64; o <<= 1) {
            int t2 = __shfl_up(sc, o, 64);
            if (lane >= o) sc += t2;
        }
        if (tid == 63) w0sum = sc;
        __syncthreads();
        int incl = sc + ((tid >= 64) ? w0sum : 0);
        int excl = incl - v;
        lcur[tid] = excl;
        int n = b * 128 + tid;
        if (n < N_NODES) {
            nodeinfo[n] = (v << 23) | (base + excl);
            dinv[n] = rsqrtf((float)v + 1.0f);  // +1 self-loop
        }
    } else {
        __syncthreads();
    }
    __syncthreads();
    for (int i = tid; i < cnt4; i += 512) {
        int4 w = buf4[i];
        int p0 = atomicAdd(&lcur[w.x >> 17], 1); lsort[p0] = w.x & 0x1FFFF;
        int p1 = atomicAdd(&lcur[w.y >> 17], 1); lsort[p1] = w.y & 0x1FFFF;
        int p2 = atomicAdd(&lcur[w.z >> 17], 1); lsort[p2] = w.z & 0x1FFFF;
        int p3 = atomicAdd(&lcur[w.w >> 17], 1); lsort[p3] = w.w & 0x1FFFF;
    }
    for (int i = (cnt4 << 2) + tid; i < count; i += 512) {
        int w = buf[base + i];
        int pos = atomicAdd(&lcur[w >> 17], 1);
        lsort[pos] = w & 0x1FFFF;
    }
    __syncthreads();
    int4* bufw4 = (int4*)(buf + base);
    const int4* lsort4 = (const int4*)lsort;
    for (int i = tid; i < cnt4; i += 512) bufw4[i] = lsort4[i];
    for (int i = (cnt4 << 2) + tid; i < count; i += 512) buf[base + i] = lsort[i];
}

// ---- LayerNorm + W1 + pre-scale by dinv (one wave per node) --------------
// Emits g1 in fp16: 32B/row -> 3.2MB table, fits one XCD's 4MB L2.
__global__ void ln_w1_kernel(const float* __restrict__ x,
                             const float* __restrict__ gamma,
                             const float* __restrict__ beta,
                             const float* __restrict__ W1,
                             const float* __restrict__ dinv,
                             __half* __restrict__ g1) {
    int wave = (blockIdx.x * blockDim.x + threadIdx.x) >> 6;
    int lane = threadIdx.x & 63;
    if (wave >= N_NODES) return;
    const float* xr = x + (size_t)wave * 128;
    float x0 = xr[lane], x1 = xr[lane + 64];

    float s1 = x0 + x1;
    float s2 = x0 * x0 + x1 * x1;
    #pragma unroll
    for (int o = 32; o; o >>= 1) {
        s1 += __shfl_xor(s1, o, 64);
        s2 += __shfl_xor(s2, o, 64);
    }
    float mu = s1 * (1.0f / 128.0f);
    float var = s2 * (1.0f / 128.0f) - mu * mu;
    float rstd = rsqrtf(var + 1e-5f);
    float xn0 = (x0 - mu) * rstd * gamma[lane] + beta[lane];
    float xn1 = (x1 - mu) * rstd * gamma[lane + 64] + beta[lane + 64];

    float p[16];
    const float* wr0 = W1 + (size_t)lane * HIDDEN;
    const float* wr1 = W1 + (size_t)(lane + 64) * HIDDEN;
    #pragma unroll
    for (int j = 0; j < 16; j++) p[j] = xn0 * wr0[j] + xn1 * wr1[j];

    // vector-halving butterfly
    float q[8];
    {
        int sel = lane & 1;
        #pragma unroll
        for (int j = 0; j < 8; j++) {
            float mine = sel ? p[j + 8] : p[j];
            float give = sel ? p[j] : p[j + 8];
            q[j] = mine + __shfl_xor(give, 1, 64);
        }
    }
    float r[4];
    {
        int sel = (lane >> 1) & 1;
        #pragma unroll
        for (int j = 0; j < 4; j++) {
            float mine = sel ? q[j + 4] : q[j];
            float give = sel ? q[j] : q[j + 4];
            r[j] = mine + __shfl_xor(give, 2, 64);
        }
    }
    float s[2];
    {
        int sel = (lane >> 2) & 1;
        #pragma unroll
        for (int j = 0; j < 2; j++) {
            float mine = sel ? r[j + 2] : r[j];
            float give = sel ? r[j] : r[j + 2];
            s[j] = mine + __shfl_xor(give, 4, 64);
        }
    }
    float t;
    {
        int sel = (lane >> 3) & 1;
        float mine = sel ? s[1] : s[0];
        float give = sel ? s[0] : s[1];
        t = mine + __shfl_xor(give, 8, 64);
    }
    t += __shfl_xor(t, 16, 64);
    t += __shfl_xor(t, 32, 64);

    if (lane < 16) {
        int f = ((lane & 1) << 3) | ((lane & 2) << 1) |
                ((lane & 4) >> 1) | ((lane & 8) >> 3);  // bitrev4
        g1[(size_t)wave * HIDDEN + f] = __float2half_rn(t * dinv[wave]);
    }
}

// ---- pull conv1 + fused finalize1: 4 nodes per wave, fp16 gather ---------
__global__ __launch_bounds__(256) void pull1_kernel(const int* __restrict__ nodeinfo,
                             const int* __restrict__ sorted_src,
                             const __half* __restrict__ g1,
                             const float* __restrict__ dinv,
                             const float* __restrict__ b1,
                             const float* __restrict__ W2,
                             const uint64_t* __restrict__ m1,
                             __half* __restrict__ g2) {
    __shared__ float sW2[HIDDEN * HIDDEN];
    if (threadIdx.x < HIDDEN * HIDDEN) sW2[threadIdx.x] = W2[threadIdx.x];
    __syncthreads();
    int n = blockIdx.x * 16 + (threadIdx.x >> 4);  // grid*16 == N_NODES
    int l = threadIdx.x & 15;
    int c = l & 3, e = l >> 2;
    uint32_t co = (uint32_t)(c * 4);
    int info = nodeinfo[n];
    int start = info & 0x7FFFFF;
    int deg = (int)((unsigned)info >> 23);

    float4 acc = make_float4(0.f, 0.f, 0.f, 0.f);
    float4 acc2 = make_float4(0.f, 0.f, 0.f, 0.f);
    if (e == 0) acc = ldh4(g1 + (uint32_t)n * HIDDEN + co);  // self
    int km = (deg > 0) ? deg - 1 : 0;
    int eb = e * 4;
    for (int kb = 0; kb < deg; kb += 16) {
        int k0 = kb + eb;
        // unconditional clamped idx loads: issue all 4 up front (MLP)
        int s0 = sorted_src[start + min(k0,     km)];
        int s1 = sorted_src[start + min(k0 + 1, km)];
        int s2 = sorted_src[start + min(k0 + 2, km)];
        int s3 = sorted_src[start + min(k0 + 3, km)];
        if (k0 < deg) {
            const float4 gv = ldh4(g1 + (uint32_t)s0 * HIDDEN + co);
            acc.x += gv.x; acc.y += gv.y; acc.z += gv.z; acc.w += gv.w;
        }
        if (k0 + 1 < deg) {
            const float4 gv = ldh4(g1 + (uint32_t)s1 * HIDDEN + co);
            acc2.x += gv.x; acc2.y += gv.y; acc2.z += gv.z; acc2.w += gv.w;
        }
        if (k0 + 2 < deg) {
            const float4 gv = ldh4(g1 + (uint32_t)s2 * HIDDEN + co);
            acc.x += gv.x; acc.y += gv.y; acc.z += gv.z; acc.w += gv.w;
        }
        if (k0 + 3 < deg) {
            const float4 gv = ldh4(g1 + (uint32_t)s3 * HIDDEN + co);
            acc2.x += gv.x; acc2.y += gv.y; acc2.z += gv.z; acc2.w += gv.w;
        }
    }
    acc.x += acc2.x; acc.y += acc2.y; acc.z += acc2.z; acc.w += acc2.w;
    // reduce over the 4 edge slots (stays within the 16-lane group)
    #pragma unroll
    for (int o = 4; o <= 8; o <<= 1) {
        acc.x += __shfl_xor(acc.x, o, 64);
        acc.y += __shfl_xor(acc.y, o, 64);
        acc.z += __shfl_xor(acc.z, o, 64);
        acc.w += __shfl_xor(acc.w, o, 64);
    }
    float di = dinv[n];
    const float4 b1c = *(const float4*)&b1[c * 4];
    uint32_t mbits = (uint32_t)(m1[n >> 2] >> ((n & 3) * 16));
    const float inv = 1.0f / 0.7f;
    float h[4];
    h[0] = ((mbits >> (c * 4 + 0)) & 1) ? fmaxf(di * acc.x + b1c.x, 0.f) * inv : 0.f;
    h[1] = ((mbits >> (c * 4 + 1)) & 1) ? fmaxf(di * acc.y + b1c.y, 0.f) * inv : 0.f;
    h[2] = ((mbits >> (c * 4 + 2)) & 1) ? fmaxf(di * acc.z + b1c.z, 0.f) * inv : 0.f;
    h[3] = ((mbits >> (c * 4 + 3)) & 1) ? fmaxf(di * acc.w + b1c.w, 0.f) * inv : 0.f;
    // h @ W2: broadcast h[i] from lanes 0..3 of this group (e==0, c=i>>2)
    int grpbase = threadIdx.x & 48;
    float4 o4 = make_float4(0.f, 0.f, 0.f, 0.f);
    #pragma unroll
    for (int i = 0; i < HIDDEN; i++) {
        float hi = __shfl(h[i & 3], grpbase + (i >> 2), 64);
        const float4 w = *(const float4*)&sW2[i * HIDDEN + c * 4];
        o4.x += hi * w.x; o4.y += hi * w.y; o4.z += hi * w.z; o4.w += hi * w.w;
    }
    if (e == 0)
        sth4(g2 + (uint32_t)n * HIDDEN + co,
             make_float4(o4.x * di, o4.y * di, o4.z * di, o4.w * di));
}

// ---- pull conv2 + fused finalize2: fp16 gather, fp32 output --------------
__global__ __launch_bounds__(256) void pull2_kernel(const int* __restrict__ nodeinfo,
                             const int* __restrict__ sorted_src,
                             const __half* __restrict__ g2,
                             const float* __restrict__ dinv,
                             const float* __restrict__ b2,
                             const uint64_t* __restrict__ m2,
                             float* __restrict__ out) {
    int n = blockIdx.x * 16 + (threadIdx.x >> 4);
    int l = threadIdx.x & 15;
    int c = l & 3, e = l >> 2;
    uint32_t co = (uint32_t)(c * 4);
    int info = nodeinfo[n];
    int start = info & 0x7FFFFF;
    int deg = (int)((unsigned)info >> 23);

    float4 acc = make_float4(0.f, 0.f, 0.f, 0.f);
    float4 acc2 = make_float4(0.f, 0.f, 0.f, 0.f);
    if (e == 0) acc = ldh4(g2 + (uint32_t)n * HIDDEN + co);  // self
    int km = (deg > 0) ? deg - 1 : 0;
    int eb = e * 4;
    for (int kb = 0; kb < deg; kb += 16) {
        int k0 = kb + eb;
        int s0 = sorted_src[start + min(k0,     km)];
        int s1 = sorted_src[start + min(k0 + 1, km)];
        int s2 = sorted_src[start + min(k0 + 2, km)];
        int s3 = sorted_src[start + min(k0 + 3, km)];
        if (k0 < deg) {
            const float4 gv = ldh4(g2 + (uint32_t)s0 * HIDDEN + co);
            acc.x += gv.x; acc.y += gv.y; acc.z += gv.z; acc.w += gv.w;
        }
        if (k0 + 1 < deg) {
            const float4 gv = ldh4(g2 + (uint32_t)s1 * HIDDEN + co);
            acc2.x += gv.x; acc2.y += gv.y; acc2.z += gv.z; acc2.w += gv.w;
        }
        if (k0 + 2 < deg) {
            const float4 gv = ldh4(g2 + (uint32_t)s2 * HIDDEN + co);
            acc.x += gv.x; acc.y += gv.y; acc.z += gv.z; acc.w += gv.w;
        }
        if (k0 + 3 < deg) {
            const float4 gv = ldh4(g2 + (uint32_t)s3 * HIDDEN + co);
            acc2.x += gv.x; acc2.y += gv.y; acc2.z += gv.z; acc2.w += gv.w;
        }
    }
    acc.x += acc2.x; acc.y += acc2.y; acc.z += acc2.z; acc.w += acc2.w;
    #pragma unroll
    for (int o = 4; o <= 8; o <<= 1) {
        acc.x += __shfl_xor(acc.x, o, 64);
        acc.y += __shfl_xor(acc.y, o, 64);
        acc.z += __shfl_xor(acc.z, o, 64);
        acc.w += __shfl_xor(acc.w, o, 64);
    }
    if (e == 0) {
        float di = dinv[n];
        const float4 b2c = *(const float4*)&b2[c * 4];
        uint32_t mbits = (uint32_t)(m2[n >> 2] >> ((n & 3) * 16));
        const float inv = 1.0f / 0.7f;
        float4 r;
        r.x = ((mbits >> (c * 4 + 0)) & 1) ? fmaxf(di * acc.x + b2c.x, 0.f) * inv : 0.f;
        r.y = ((mbits >> (c * 4 + 1)) & 1) ? fmaxf(di * acc.y + b2c.y, 0.f) * inv : 0.f;
        r.z = ((mbits >> (c * 4 + 2)) & 1) ? fmaxf(di * acc.z + b2c.z, 0.f) * inv : 0.f;
        r.w = ((mbits >> (c * 4 + 3)) & 1) ? fmaxf(di * acc.w + b2c.w, 0.f) * inv : 0.f;
        *(float4*)&out[(uint32_t)n * HIDDEN + co] = r;
    }
}

extern "C" void kernel_launch(void* const* d_in, const int* in_sizes, int n_in,
                              void* d_out, int out_size, void* d_ws, size_t ws_size,
                              hipStream_t stream) {
    const float* x     = (const float*)d_in[0];
    const int*   ei    = (const int*)d_in[1];
    const float* gamma = (const float*)d_in[2];
    const float* beta  = (const float*)d_in[3];
    const float* W1    = (const float*)d_in[4];
    const float* b1    = (const float*)d_in[5];
    const float* W2    = (const float*)d_in[6];
    const float* b2    = (const float*)d_in[7];
    float* out = (float*)d_out;
    const int* src = ei;
    const int* dst = ei + N_EDGES;

    uint32_t dk1_0, dk1_1, dk2_0, dk2_1;
    threefry2x32(0u, 42u, 0u, 0u, dk1_0, dk1_1);
    threefry2x32(0u, 42u, 0u, 1u, dk2_0, dk2_1);

    // ws layout (4B elems): gcursor[1024] | nodeinfo[100k] | dinv[100k] |
    // buf[NBKT*CAP] | g1h[1.6M half = 800k int] | g2h[800k int] |
    // m1[25k ull] | m2[25k ull]  (~36MB)
    int*      gcursor  = (int*)d_ws;
    int*      nodeinfo = gcursor + 1024;
    float*    dinv     = (float*)(nodeinfo + N_NODES);
    int*      buf      = (int*)(dinv + N_NODES);
    __half*   g1h      = (__half*)(buf + (size_t)NBKT * CAP);
    __half*   g2h      = g1h + (size_t)N_NODES * HIDDEN;
    uint64_t* m1       = (uint64_t*)(g2h + (size_t)N_NODES * HIDDEN);
    uint64_t* m2       = m1 + (NMASK >> 6);

    const int NB_W  = N_NODES / 4;                     // 25000 (ln_w1: 4 waves/block)
    const int NB_PULL = N_NODES / 16;                  // 6250 (pull: 16 nodes/block)
    const int NB_P1 = (N_EDGES + P1_EPB - 1) / P1_EPB; // 782

    initcur_kernel<<<1, 1024, 0, stream>>>(gcursor);
    dropmask_kernel<<<(2 * NMASK) / 256, 256, 0, stream>>>(m1, m2,
                                                           dk1_0, dk1_1,
                                                           dk2_0, dk2_1);
    part1_kernel<<<NB_P1, 512, 0, stream>>>(src, dst, gcursor, buf);
    part2_kernel<<<NBKT, 512, 0, stream>>>(gcursor, buf, nodeinfo, dinv);
    ln_w1_kernel<<<NB_W, 256, 0, stream>>>(x, gamma, beta, W1, dinv, g1h);
    pull1_kernel<<<NB_PULL, 256, 0, stream>>>(nodeinfo, buf, g1h,
                                              dinv, b1, W2, m1, g2h);
    pull2_kernel<<<NB_PULL, 256, 0, stream>>>(nodeinfo, buf, g2h,
                                              dinv, b2, m2, out);
}

// Round 5
// 325.492 us; speedup vs baseline: 1.3152x; 1.0095x over previous
//
#include <hip/hip_runtime.h>
#include <hip/hip_fp16.h>
#include <stdint.h>
#include <stddef.h>

#define N_NODES 100000
#define N_EDGES 6400000
#define HIDDEN 16
#define NBKT 782          /* ceil(100000/128) coarse buckets of 128 nodes */
#define CAP 8704          /* bucket region capacity: mean 8184 + 5.7 sigma */
#define P1_EPB 8192       /* edges per part1 block */
#define NMASK 1600000     /* N_NODES*HIDDEN */

typedef _Float16 f16x8 __attribute__((ext_vector_type(8)));
typedef float f32x4 __attribute__((ext_vector_type(4)));

__host__ __device__ inline uint32_t rotl32(uint32_t x, int n) {
    return (x << n) | (x >> (32 - n));
}

// Exact JAX threefry2x32 (20 rounds)
__host__ __device__ inline void threefry2x32(uint32_t k0, uint32_t k1,
                                             uint32_t x0, uint32_t x1,
                                             uint32_t& o0, uint32_t& o1) {
    uint32_t k2 = k0 ^ k1 ^ 0x1BD11BDAu;
    x0 += k0; x1 += k1;
    x0 += x1; x1 = rotl32(x1, 13); x1 ^= x0;
    x0 += x1; x1 = rotl32(x1, 15); x1 ^= x0;
    x0 += x1; x1 = rotl32(x1, 26); x1 ^= x0;
    x0 += x1; x1 = rotl32(x1,  6); x1 ^= x0;
    x0 += k1; x1 += k2 + 1u;
    x0 += x1; x1 = rotl32(x1, 17); x1 ^= x0;
    x0 += x1; x1 = rotl32(x1, 29); x1 ^= x0;
    x0 += x1; x1 = rotl32(x1, 16); x1 ^= x0;
    x0 += x1; x1 = rotl32(x1, 24); x1 ^= x0;
    x0 += k2; x1 += k0 + 2u;
    x0 += x1; x1 = rotl32(x1, 13); x1 ^= x0;
    x0 += x1; x1 = rotl32(x1, 15); x1 ^= x0;
    x0 += x1; x1 = rotl32(x1, 26); x1 ^= x0;
    x0 += x1; x1 = rotl32(x1,  6); x1 ^= x0;
    x0 += k0; x1 += k1 + 3u;
    x0 += x1; x1 = rotl32(x1, 17); x1 ^= x0;
    x0 += x1; x1 = rotl32(x1, 29); x1 ^= x0;
    x0 += x1; x1 = rotl32(x1, 16); x1 ^= x0;
    x0 += x1; x1 = rotl32(x1, 24); x1 ^= x0;
    x0 += k1; x1 += k2 + 4u;
    x0 += x1; x1 = rotl32(x1, 13); x1 ^= x0;
    x0 += x1; x1 = rotl32(x1, 15); x1 ^= x0;
    x0 += x1; x1 = rotl32(x1, 26); x1 ^= x0;
    x0 += x1; x1 = rotl32(x1,  6); x1 ^= x0;
    x0 += k2; x1 += k0 + 5u;
    o0 = x0; o1 = x1;
}

// ---- fp16 row helpers (gather tables are fp16; accumulation is fp32) -----
__device__ inline float4 ldh4(const __half* p) {
    uint2 u = *(const uint2*)p;                 // 8B aligned load
    __half2 h0 = *(__half2*)&u.x;
    __half2 h1 = *(__half2*)&u.y;
    float2 a = __half22float2(h0), b = __half22float2(h1);
    return make_float4(a.x, a.y, b.x, b.y);
}
__device__ inline void sth4(__half* p, float4 v) {
    __half2 h0 = __floats2half2_rn(v.x, v.y);
    __half2 h1 = __floats2half2_rn(v.z, v.w);
    uint2 u;
    u.x = *(uint32_t*)&h0; u.y = *(uint32_t*)&h1;
    *(uint2*)p = u;
}

// ---- dropout keep-bit masks, 1 threefry eval per lane, ballot-packed -----
__global__ __launch_bounds__(256) void dropmask_kernel(uint64_t* __restrict__ m1,
                                                       uint64_t* __restrict__ m2,
                                                       uint32_t k10, uint32_t k11,
                                                       uint32_t k20, uint32_t k21) {
    int g = blockIdx.x * blockDim.x + threadIdx.x;   // [0, 2*NMASK)
    int lane = threadIdx.x & 63;
    bool first = g < NMASK;
    uint32_t j = first ? (uint32_t)g : (uint32_t)(g - NMASK);
    uint32_t a, b;
    threefry2x32(first ? k10 : k20, first ? k11 : k21, 0u, j, a, b);
    uint32_t bits = a ^ b;
    float u = __uint_as_float((bits >> 9) | 0x3F800000u) - 1.0f;
    unsigned long long m = __ballot(u >= 0.3f);
    if (lane == 0) {
        int gw = g >> 6;
        if (first) m1[gw] = m;
        else       m2[gw - (NMASK >> 6)] = m;
    }
}

// ---- gcursor[b] = b*CAP (fixed-capacity bucket regions, no scan) ---------
__global__ void initcur_kernel(int* __restrict__ gcursor) {
    int b = threadIdx.x;
    if (b < NBKT) gcursor[b] = b * CAP;
}

// ---- partition pass 1: LDS counting sort, int4 loads, shuffle scan -------
// hist -> wave-shuffle scan (5 barriers total) -> per-bucket global cursor
// reservation -> LDS lsort staging -> 16-lane-group coalesced run flush.
// lsort staging is load-bearing: it turns 6.4M scattered 4B stores into
// contiguous ~42B runs (R3 measured 172MB writes without it vs 43MB with).
__global__ __launch_bounds__(512) void part1_kernel(const int* __restrict__ src,
                                                    const int* __restrict__ dst,
                                                    int* __restrict__ gcursor,
                                                    int* __restrict__ buf) {
    __shared__ int lhist[NBKT], lbase[NBKT], lstart[NBKT], lcur[NBKT];
    __shared__ int wsum[8];
    __shared__ int lsort[P1_EPB];
    int tid = threadIdx.x;
    const int NV4 = N_EDGES >> 2;                 // 1.6M int4 groups
    int base4 = blockIdx.x * (P1_EPB >> 2);       // 2048 int4 per block
    const int4* dst4 = (const int4*)dst;
    const int4* src4 = (const int4*)src;

    for (int b = tid; b < NBKT; b += 512) lhist[b] = 0;
    __syncthreads();
    #pragma unroll
    for (int i = 0; i < 4; i++) {
        int e4 = base4 + i * 512 + tid;
        if (e4 < NV4) {
            int4 d = dst4[e4];
            atomicAdd(&lhist[d.x >> 7], 1);
            atomicAdd(&lhist[d.y >> 7], 1);
            atomicAdd(&lhist[d.z >> 7], 1);
            atomicAdd(&lhist[d.w >> 7], 1);
        }
    }
    __syncthreads();
    // exclusive scan over 782 bucket counts: thread t owns buckets 2t,2t+1
    int i0 = tid * 2, i1 = i0 + 1;
    int c0 = (i0 < NBKT) ? lhist[i0] : 0;
    int c1 = (i1 < NBKT) ? lhist[i1] : 0;
    int v = c0 + c1;
    int lane = tid & 63, wid = tid >> 6;
    int sc = v;
    #pragma unroll
    for (int o = 1; o < 64; o <<= 1) {
        int t2 = __shfl_up(sc, o, 64);
        if (lane >= o) sc += t2;
    }
    if (lane == 63) wsum[wid] = sc;
    __syncthreads();
    int wo = 0;
    #pragma unroll
    for (int w = 0; w < 8; w++) wo += (w < wid) ? wsum[w] : 0;
    int excl = sc - v + wo;
    if (i0 < NBKT) { lstart[i0] = excl;      lcur[i0] = excl; }
    if (i1 < NBKT) { lstart[i1] = excl + c0; lcur[i1] = excl + c0; }
    for (int b = tid; b < NBKT; b += 512) {
        int c = lhist[b];
        lbase[b] = c ? atomicAdd(&gcursor[b], c) : 0;
    }
    __syncthreads();
    #pragma unroll
    for (int i = 0; i < 4; i++) {
        int e4 = base4 + i * 512 + tid;
        if (e4 < NV4) {
            int4 d = dst4[e4];
            int4 s = src4[e4];
            int p0 = atomicAdd(&lcur[d.x >> 7], 1);
            lsort[p0] = ((d.x & 127) << 17) | s.x;
            int p1 = atomicAdd(&lcur[d.y >> 7], 1);
            lsort[p1] = ((d.y & 127) << 17) | s.y;
            int p2 = atomicAdd(&lcur[d.z >> 7], 1);
            lsort[p2] = ((d.z & 127) << 17) | s.z;
            int p3 = atomicAdd(&lcur[d.w >> 7], 1);
            lsort[p3] = ((d.w & 127) << 17) | s.w;
        }
    }
    __syncthreads();
    int grp = tid >> 4, gl = tid & 15;
    for (int b = grp; b < NBKT; b += 32) {
        int st = lstart[b], c = lhist[b], gb = lbase[b];
        int lim = (b + 1) * CAP;
        for (int k = gl; k < c; k += 16) {
            int pos = gb + k;
            if (pos < lim)   // capacity guard (P ~ 5e-6 total)
                buf[pos] = lsort[st + k];
        }
    }
}

// ---- part2: per-bucket fine sort in LDS; int4 loads, shuffle scan --------
__global__ __launch_bounds__(512) void part2_kernel(const int* __restrict__ gcursor,
                                                    int* __restrict__ buf,
                                                    int* __restrict__ nodeinfo,
                                                    float* __restrict__ dinv) {
    __shared__ int lcnt[128], lcur[128];
    __shared__ int w0sum;
    __shared__ int lsort[CAP];
    int b = blockIdx.x, tid = threadIdx.x;
    int base = b * CAP;                 // CAP%4==0 -> 16B aligned
    int end = gcursor[b];
    int count = end - base;
    int cnt4 = count >> 2;
    const int4* buf4 = (const int4*)(buf + base);
    if (tid < 128) lcnt[tid] = 0;
    __syncthreads();
    for (int i = tid; i < cnt4; i += 512) {
        int4 w = buf4[i];
        atomicAdd(&lcnt[w.x >> 17], 1);
        atomicAdd(&lcnt[w.y >> 17], 1);
        atomicAdd(&lcnt[w.z >> 17], 1);
        atomicAdd(&lcnt[w.w >> 17], 1);
    }
    for (int i = (cnt4 << 2) + tid; i < count; i += 512)
        atomicAdd(&lcnt[buf[base + i] >> 17], 1);
    __syncthreads();
    // shuffle scan over 128 counters (waves 0 and 1)
    if (tid < 128) {
        int v = lcnt[tid];
        int lane = tid & 63;
        int sc = v;
        #pragma unroll
        for (int o = 1; o < 64; o <<= 1) {
            int t2 = __shfl_up(sc, o, 64);
            if (lane >= o) sc += t2;
        }
        if (tid == 63) w0sum = sc;
        __syncthreads();
        int incl = sc + ((tid >= 64) ? w0sum : 0);
        int excl = incl - v;
        lcur[tid] = excl;
        int n = b * 128 + tid;
        if (n < N_NODES) {
            nodeinfo[n] = (v << 23) | (base + excl);
            dinv[n] = rsqrtf((float)v + 1.0f);  // +1 self-loop
        }
    } else {
        __syncthreads();
    }
    __syncthreads();
    for (int i = tid; i < cnt4; i += 512) {
        int4 w = buf4[i];
        int p0 = atomicAdd(&lcur[w.x >> 17], 1); lsort[p0] = w.x & 0x1FFFF;
        int p1 = atomicAdd(&lcur[w.y >> 17], 1); lsort[p1] = w.y & 0x1FFFF;
        int p2 = atomicAdd(&lcur[w.z >> 17], 1); lsort[p2] = w.z & 0x1FFFF;
        int p3 = atomicAdd(&lcur[w.w >> 17], 1); lsort[p3] = w.w & 0x1FFFF;
    }
    for (int i = (cnt4 << 2) + tid; i < count; i += 512) {
        int w = buf[base + i];
        int pos = atomicAdd(&lcur[w >> 17], 1);
        lsort[pos] = w & 0x1FFFF;
    }
    __syncthreads();
    int4* bufw4 = (int4*)(buf + base);
    const int4* lsort4 = (const int4*)lsort;
    for (int i = tid; i < cnt4; i += 512) bufw4[i] = lsort4[i];
    for (int i = (cnt4 << 2) + tid; i < count; i += 512) buf[base + i] = lsort[i];
}

// ---- LayerNorm + W1 via MFMA: 64 nodes per 256-thread block --------------
// Phase A: thread (r=tid>>2, q=tid&3) LayerNorms a 32-elem quarter of row r
// (float4 loads, 4-lane shfl reduce) and writes f16 xn into LDS [64][136]
// (pad 8 f16 -> bank-uniform b128 on both write and A-frag read sides).
// W1^T staged as f16 [16][136]. Phase B: wave w computes rows 16w..16w+15
// with 4x mfma_f32_16x16x32_f16 (K=128), scales by dinv, stores f16 g1.
// Replaces ~120 wave-instrs/node (shuffle butterfly) with ~10/node.
#define XSTR 136
__global__ __launch_bounds__(256) void ln_w1_kernel(const float* __restrict__ x,
                             const float* __restrict__ gamma,
                             const float* __restrict__ beta,
                             const float* __restrict__ W1,
                             const float* __restrict__ dinv,
                             __half* __restrict__ g1) {
    __shared__ __align__(16) _Float16 xnh[64 * XSTR];   // 17408 B
    __shared__ __align__(16) _Float16 w1t[16 * XSTR];   //  4352 B
    int tid = threadIdx.x;
    int r = tid >> 2, q = tid & 3;
    int node = blockIdx.x * 64 + r;

    // stage W1^T as f16: thread (n=tid&15, kb=tid>>4) covers 8 k's
    {
        int n = tid & 15, kb = tid >> 4;
        f16x8 wv;
        #pragma unroll
        for (int j = 0; j < 8; j++)
            wv[j] = (_Float16)W1[(kb * 8 + j) * 16 + n];
        *(f16x8*)&w1t[n * XSTR + kb * 8] = wv;
    }

    // load quarter-row, LN stats over 4 lanes
    bool valid = node < N_NODES;
    const float4* xr4 = (const float4*)(x + (size_t)node * 128 + q * 32);
    float4 xv[8];
    #pragma unroll
    for (int j = 0; j < 8; j++)
        xv[j] = valid ? xr4[j] : make_float4(0.f, 0.f, 0.f, 0.f);
    float s1 = 0.f, s2 = 0.f;
    #pragma unroll
    for (int j = 0; j < 8; j++) {
        s1 += xv[j].x + xv[j].y + xv[j].z + xv[j].w;
        s2 += xv[j].x * xv[j].x + xv[j].y * xv[j].y
            + xv[j].z * xv[j].z + xv[j].w * xv[j].w;
    }
    s1 += __shfl_xor(s1, 1, 64); s1 += __shfl_xor(s1, 2, 64);
    s2 += __shfl_xor(s2, 1, 64); s2 += __shfl_xor(s2, 2, 64);
    float mu = s1 * (1.0f / 128.0f);
    float var = s2 * (1.0f / 128.0f) - mu * mu;
    float rstd = rsqrtf(var + 1e-5f);

    const float4* g4 = (const float4*)(gamma + q * 32);
    const float4* b4 = (const float4*)(beta + q * 32);
    #pragma unroll
    for (int t = 0; t < 4; t++) {
        f16x8 h;
        #pragma unroll
        for (int u = 0; u < 2; u++) {
            int j = t * 2 + u;
            float4 gv = g4[j], bv = b4[j];
            h[u * 4 + 0] = (_Float16)((xv[j].x - mu) * rstd * gv.x + bv.x);
            h[u * 4 + 1] = (_Float16)((xv[j].y - mu) * rstd * gv.y + bv.y);
            h[u * 4 + 2] = (_Float16)((xv[j].z - mu) * rstd * gv.z + bv.z);
            h[u * 4 + 3] = (_Float16)((xv[j].w - mu) * rstd * gv.w + bv.w);
        }
        *(f16x8*)&xnh[r * XSTR + q * 32 + t * 8] = h;
    }
    __syncthreads();

    // MFMA phase: wave w -> rows 16w..16w+15
    int l = tid & 63, w = tid >> 6;
    int am = l & 15, ak = l >> 4;   // A row / k-subgroup
    const _Float16* abase = &xnh[(w * 16 + am) * XSTR + ak * 8];
    const _Float16* bbase = &w1t[am * XSTR + ak * 8];
    f32x4 acc = {0.f, 0.f, 0.f, 0.f};
    #pragma unroll
    for (int kk = 0; kk < 4; kk++) {
        f16x8 av = *(const f16x8*)(abase + kk * 32);
        f16x8 bv = *(const f16x8*)(bbase + kk * 32);
        acc = __builtin_amdgcn_mfma_f32_16x16x32_f16(av, bv, acc, 0, 0, 0);
    }
    _Float16* g1h = (_Float16*)g1;
    #pragma unroll
    for (int reg = 0; reg < 4; reg++) {
        int row = w * 16 + ak * 4 + reg;            // C: row=(l>>4)*4+reg
        int nn = blockIdx.x * 64 + row;
        if (nn < N_NODES)
            g1h[nn * 16 + am] = (_Float16)(acc[reg] * dinv[nn]);  // col=l&15
    }
}

// ---- pull conv1 + fused finalize1: 4 nodes per wave, fp16 gather ---------
__global__ __launch_bounds__(256) void pull1_kernel(const int* __restrict__ nodeinfo,
                             const int* __restrict__ sorted_src,
                             const __half* __restrict__ g1,
                             const float* __restrict__ dinv,
                             const float* __restrict__ b1,
                             const float* __restrict__ W2,
                             const uint64_t* __restrict__ m1,
                             __half* __restrict__ g2) {
    __shared__ float sW2[HIDDEN * HIDDEN];
    if (threadIdx.x < HIDDEN * HIDDEN) sW2[threadIdx.x] = W2[threadIdx.x];
    __syncthreads();
    int n = blockIdx.x * 16 + (threadIdx.x >> 4);  // grid*16 == N_NODES
    int l = threadIdx.x & 15;
    int c = l & 3, e = l >> 2;
    uint32_t co = (uint32_t)(c * 4);
    int info = nodeinfo[n];
    int start = info & 0x7FFFFF;
    int deg = (int)((unsigned)info >> 23);

    float4 acc = make_float4(0.f, 0.f, 0.f, 0.f);
    float4 acc2 = make_float4(0.f, 0.f, 0.f, 0.f);
    if (e == 0) acc = ldh4(g1 + (uint32_t)n * HIDDEN + co);  // self
    int km = (deg > 0) ? deg - 1 : 0;
    int eb = e * 4;
    for (int kb = 0; kb < deg; kb += 16) {
        int k0 = kb + eb;
        // unconditional clamped idx loads: issue all 4 up front (MLP)
        int s0 = sorted_src[start + min(k0,     km)];
        int s1 = sorted_src[start + min(k0 + 1, km)];
        int s2 = sorted_src[start + min(k0 + 2, km)];
        int s3 = sorted_src[start + min(k0 + 3, km)];
        if (k0 < deg) {
            const float4 gv = ldh4(g1 + (uint32_t)s0 * HIDDEN + co);
            acc.x += gv.x; acc.y += gv.y; acc.z += gv.z; acc.w += gv.w;
        }
        if (k0 + 1 < deg) {
            const float4 gv = ldh4(g1 + (uint32_t)s1 * HIDDEN + co);
            acc2.x += gv.x; acc2.y += gv.y; acc2.z += gv.z; acc2.w += gv.w;
        }
        if (k0 + 2 < deg) {
            const float4 gv = ldh4(g1 + (uint32_t)s2 * HIDDEN + co);
            acc.x += gv.x; acc.y += gv.y; acc.z += gv.z; acc.w += gv.w;
        }
        if (k0 + 3 < deg) {
            const float4 gv = ldh4(g1 + (uint32_t)s3 * HIDDEN + co);
            acc2.x += gv.x; acc2.y += gv.y; acc2.z += gv.z; acc2.w += gv.w;
        }
    }
    acc.x += acc2.x; acc.y += acc2.y; acc.z += acc2.z; acc.w += acc2.w;
    // reduce over the 4 edge slots (stays within the 16-lane group)
    #pragma unroll
    for (int o = 4; o <= 8; o <<= 1) {
        acc.x += __shfl_xor(acc.x, o, 64);
        acc.y += __shfl_xor(acc.y, o, 64);
        acc.z += __shfl_xor(acc.z, o, 64);
        acc.w += __shfl_xor(acc.w, o, 64);
    }
    float di = dinv[n];
    const float4 b1c = *(const float4*)&b1[c * 4];
    uint32_t mbits = (uint32_t)(m1[n >> 2] >> ((n & 3) * 16));
    const float inv = 1.0f / 0.7f;
    float h[4];
    h[0] = ((mbits >> (c * 4 + 0)) & 1) ? fmaxf(di * acc.x + b1c.x, 0.f) * inv : 0.f;
    h[1] = ((mbits >> (c * 4 + 1)) & 1) ? fmaxf(di * acc.y + b1c.y, 0.f) * inv : 0.f;
    h[2] = ((mbits >> (c * 4 + 2)) & 1) ? fmaxf(di * acc.z + b1c.z, 0.f) * inv : 0.f;
    h[3] = ((mbits >> (c * 4 + 3)) & 1) ? fmaxf(di * acc.w + b1c.w, 0.f) * inv : 0.f;
    // h @ W2: broadcast h[i] from lanes 0..3 of this group (e==0, c=i>>2)
    int grpbase = threadIdx.x & 48;
    float4 o4 = make_float4(0.f, 0.f, 0.f, 0.f);
    #pragma unroll
    for (int i = 0; i < HIDDEN; i++) {
        float hi = __shfl(h[i & 3], grpbase + (i >> 2), 64);
        const float4 w = *(const float4*)&sW2[i * HIDDEN + c * 4];
        o4.x += hi * w.x; o4.y += hi * w.y; o4.z += hi * w.z; o4.w += hi * w.w;
    }
    if (e == 0)
        sth4(g2 + (uint32_t)n * HIDDEN + co,
             make_float4(o4.x * di, o4.y * di, o4.z * di, o4.w * di));
}

// ---- pull conv2 + fused finalize2: fp16 gather, fp32 output --------------
__global__ __launch_bounds__(256) void pull2_kernel(const int* __restrict__ nodeinfo,
                             const int* __restrict__ sorted_src,
                             const __half* __restrict__ g2,
                             const float* __restrict__ dinv,
                             const float* __restrict__ b2,
                             const uint64_t* __restrict__ m2,
                             float* __restrict__ out) {
    int n = blockIdx.x * 16 + (threadIdx.x >> 4);
    int l = threadIdx.x & 15;
    int c = l & 3, e = l >> 2;
    uint32_t co = (uint32_t)(c * 4);
    int info = nodeinfo[n];
    int start = info & 0x7FFFFF;
    int deg = (int)((unsigned)info >> 23);

    float4 acc = make_float4(0.f, 0.f, 0.f, 0.f);
    float4 acc2 = make_float4(0.f, 0.f, 0.f, 0.f);
    if (e == 0) acc = ldh4(g2 + (uint32_t)n * HIDDEN + co);  // self
    int km = (deg > 0) ? deg - 1 : 0;
    int eb = e * 4;
    for (int kb = 0; kb < deg; kb += 16) {
        int k0 = kb + eb;
        int s0 = sorted_src[start + min(k0,     km)];
        int s1 = sorted_src[start + min(k0 + 1, km)];
        int s2 = sorted_src[start + min(k0 + 2, km)];
        int s3 = sorted_src[start + min(k0 + 3, km)];
        if (k0 < deg) {
            const float4 gv = ldh4(g2 + (uint32_t)s0 * HIDDEN + co);
            acc.x += gv.x; acc.y += gv.y; acc.z += gv.z; acc.w += gv.w;
        }
        if (k0 + 1 < deg) {
            const float4 gv = ldh4(g2 + (uint32_t)s1 * HIDDEN + co);
            acc2.x += gv.x; acc2.y += gv.y; acc2.z += gv.z; acc2.w += gv.w;
        }
        if (k0 + 2 < deg) {
            const float4 gv = ldh4(g2 + (uint32_t)s2 * HIDDEN + co);
            acc.x += gv.x; acc.y += gv.y; acc.z += gv.z; acc.w += gv.w;
        }
        if (k0 + 3 < deg) {
            const float4 gv = ldh4(g2 + (uint32_t)s3 * HIDDEN + co);
            acc2.x += gv.x; acc2.y += gv.y; acc2.z += gv.z; acc2.w += gv.w;
        }
    }
    acc.x += acc2.x; acc.y += acc2.y; acc.z += acc2.z; acc.w += acc2.w;
    #pragma unroll
    for (int o = 4; o <= 8; o <<= 1) {
        acc.x += __shfl_xor(acc.x, o, 64);
        acc.y += __shfl_xor(acc.y, o, 64);
        acc.z += __shfl_xor(acc.z, o, 64);
        acc.w += __shfl_xor(acc.w, o, 64);
    }
    if (e == 0) {
        float di = dinv[n];
        const float4 b2c = *(const float4*)&b2[c * 4];
        uint32_t mbits = (uint32_t)(m2[n >> 2] >> ((n & 3) * 16));
        const float inv = 1.0f / 0.7f;
        float4 r;
        r.x = ((mbits >> (c * 4 + 0)) & 1) ? fmaxf(di * acc.x + b2c.x, 0.f) * inv : 0.f;
        r.y = ((mbits >> (c * 4 + 1)) & 1) ? fmaxf(di * acc.y + b2c.y, 0.f) * inv : 0.f;
        r.z = ((mbits >> (c * 4 + 2)) & 1) ? fmaxf(di * acc.z + b2c.z, 0.f) * inv : 0.f;
        r.w = ((mbits >> (c * 4 + 3)) & 1) ? fmaxf(di * acc.w + b2c.w, 0.f) * inv : 0.f;
        *(float4*)&out[(uint32_t)n * HIDDEN + co] = r;
    }
}

extern "C" void kernel_launch(void* const* d_in, const int* in_sizes, int n_in,
                              void* d_out, int out_size, void* d_ws, size_t ws_size,
                              hipStream_t stream) {
    const float* x     = (const float*)d_in[0];
    const int*   ei    = (const int*)d_in[1];
    const float* gamma = (const float*)d_in[2];
    const float* beta  = (const float*)d_in[3];
    const float* W1    = (const float*)d_in[4];
    const float* b1    = (const float*)d_in[5];
    const float* W2    = (const float*)d_in[6];
    const float* b2    = (const float*)d_in[7];
    float* out = (float*)d_out;
    const int* src = ei;
    const int* dst = ei + N_EDGES;

    uint32_t dk1_0, dk1_1, dk2_0, dk2_1;
    threefry2x32(0u, 42u, 0u, 0u, dk1_0, dk1_1);
    threefry2x32(0u, 42u, 0u, 1u, dk2_0, dk2_1);

    // ws layout (4B elems): gcursor[1024] | nodeinfo[100k] | dinv[100k] |
    // buf[NBKT*CAP] | g1h[1.6M half = 800k int] | g2h[800k int] |
    // m1[25k ull] | m2[25k ull]  (~36MB)
    int*      gcursor  = (int*)d_ws;
    int*      nodeinfo = gcursor + 1024;
    float*    dinv     = (float*)(nodeinfo + N_NODES);
    int*      buf      = (int*)(dinv + N_NODES);
    __half*   g1h      = (__half*)(buf + (size_t)NBKT * CAP);
    __half*   g2h      = g1h + (size_t)N_NODES * HIDDEN;
    uint64_t* m1       = (uint64_t*)(g2h + (size_t)N_NODES * HIDDEN);
    uint64_t* m2       = m1 + (NMASK >> 6);

    const int NB_LN = (N_NODES + 63) / 64;             // 1563 (64 nodes/block)
    const int NB_PULL = N_NODES / 16;                  // 6250 (pull: 16 nodes/block)
    const int NB_P1 = (N_EDGES + P1_EPB - 1) / P1_EPB; // 782

    initcur_kernel<<<1, 1024, 0, stream>>>(gcursor);
    dropmask_kernel<<<(2 * NMASK) / 256, 256, 0, stream>>>(m1, m2,
                                                           dk1_0, dk1_1,
                                                           dk2_0, dk2_1);
    part1_kernel<<<NB_P1, 512, 0, stream>>>(src, dst, gcursor, buf);
    part2_kernel<<<NBKT, 512, 0, stream>>>(gcursor, buf, nodeinfo, dinv);
    ln_w1_kernel<<<NB_LN, 256, 0, stream>>>(x, gamma, beta, W1, dinv, g1h);
    pull1_kernel<<<NB_PULL, 256, 0, stream>>>(nodeinfo, buf, g1h,
                                              dinv, b1, W2, m1, g2h);
    pull2_kernel<<<NB_PULL, 256, 0, stream>>>(nodeinfo, buf, g2h,
                                              dinv, b2, m2, out);
}

// Round 6
// 315.650 us; speedup vs baseline: 1.3562x; 1.0312x over previous
//
#include <hip/hip_runtime.h>
#include <hip/hip_fp16.h>
#include <stdint.h>
#include <stddef.h>

#define N_NODES 100000
#define N_EDGES 6400000
#define HIDDEN 16
#define NBKT 782          /* ceil(100000/128) coarse buckets of 128 nodes */
#define CAP 8704          /* bucket region capacity: mean 8184 + 5.7 sigma */
#define P1_EPB 8192       /* edges per part1 block */
#define NMASK 1600000     /* N_NODES*HIDDEN */

typedef _Float16 f16x8 __attribute__((ext_vector_type(8)));
typedef float f32x4 __attribute__((ext_vector_type(4)));

__host__ __device__ inline uint32_t rotl32(uint32_t x, int n) {
    return (x << n) | (x >> (32 - n));
}

// Exact JAX threefry2x32 (20 rounds)
__host__ __device__ inline void threefry2x32(uint32_t k0, uint32_t k1,
                                             uint32_t x0, uint32_t x1,
                                             uint32_t& o0, uint32_t& o1) {
    uint32_t k2 = k0 ^ k1 ^ 0x1BD11BDAu;
    x0 += k0; x1 += k1;
    x0 += x1; x1 = rotl32(x1, 13); x1 ^= x0;
    x0 += x1; x1 = rotl32(x1, 15); x1 ^= x0;
    x0 += x1; x1 = rotl32(x1, 26); x1 ^= x0;
    x0 += x1; x1 = rotl32(x1,  6); x1 ^= x0;
    x0 += k1; x1 += k2 + 1u;
    x0 += x1; x1 = rotl32(x1, 17); x1 ^= x0;
    x0 += x1; x1 = rotl32(x1, 29); x1 ^= x0;
    x0 += x1; x1 = rotl32(x1, 16); x1 ^= x0;
    x0 += x1; x1 = rotl32(x1, 24); x1 ^= x0;
    x0 += k2; x1 += k0 + 2u;
    x0 += x1; x1 = rotl32(x1, 13); x1 ^= x0;
    x0 += x1; x1 = rotl32(x1, 15); x1 ^= x0;
    x0 += x1; x1 = rotl32(x1, 26); x1 ^= x0;
    x0 += x1; x1 = rotl32(x1,  6); x1 ^= x0;
    x0 += k0; x1 += k1 + 3u;
    x0 += x1; x1 = rotl32(x1, 17); x1 ^= x0;
    x0 += x1; x1 = rotl32(x1, 29); x1 ^= x0;
    x0 += x1; x1 = rotl32(x1, 16); x1 ^= x0;
    x0 += x1; x1 = rotl32(x1, 24); x1 ^= x0;
    x0 += k1; x1 += k2 + 4u;
    x0 += x1; x1 = rotl32(x1, 13); x1 ^= x0;
    x0 += x1; x1 = rotl32(x1, 15); x1 ^= x0;
    x0 += x1; x1 = rotl32(x1, 26); x1 ^= x0;
    x0 += x1; x1 = rotl32(x1,  6); x1 ^= x0;
    x0 += k2; x1 += k0 + 5u;
    o0 = x0; o1 = x1;
}

// ---- dropout keep-bit masks, 1 threefry eval per lane, ballot-packed -----
__global__ __launch_bounds__(256) void dropmask_kernel(uint64_t* __restrict__ m1,
                                                       uint64_t* __restrict__ m2,
                                                       uint32_t k10, uint32_t k11,
                                                       uint32_t k20, uint32_t k21) {
    int g = blockIdx.x * blockDim.x + threadIdx.x;   // [0, 2*NMASK)
    int lane = threadIdx.x & 63;
    bool first = g < NMASK;
    uint32_t j = first ? (uint32_t)g : (uint32_t)(g - NMASK);
    uint32_t a, b;
    threefry2x32(first ? k10 : k20, first ? k11 : k21, 0u, j, a, b);
    uint32_t bits = a ^ b;
    float u = __uint_as_float((bits >> 9) | 0x3F800000u) - 1.0f;
    unsigned long long m = __ballot(u >= 0.3f);
    if (lane == 0) {
        int gw = g >> 6;
        if (first) m1[gw] = m;
        else       m2[gw - (NMASK >> 6)] = m;
    }
}

// ---- gcursor[b] = b*CAP (fixed-capacity bucket regions, no scan) ---------
__global__ void initcur_kernel(int* __restrict__ gcursor) {
    int b = threadIdx.x;
    if (b < NBKT) gcursor[b] = b * CAP;
}

// ---- partition pass 1: LDS counting sort, int4 loads, shuffle scan -------
// lsort staging is load-bearing: it turns 6.4M scattered 4B stores into
// contiguous ~42B runs (R3 measured 172MB writes without it vs 43MB with).
__global__ __launch_bounds__(512) void part1_kernel(const int* __restrict__ src,
                                                    const int* __restrict__ dst,
                                                    int* __restrict__ gcursor,
                                                    int* __restrict__ buf) {
    __shared__ int lhist[NBKT], lbase[NBKT], lstart[NBKT], lcur[NBKT];
    __shared__ int wsum[8];
    __shared__ int lsort[P1_EPB];
    int tid = threadIdx.x;
    const int NV4 = N_EDGES >> 2;                 // 1.6M int4 groups
    int base4 = blockIdx.x * (P1_EPB >> 2);       // 2048 int4 per block
    const int4* dst4 = (const int4*)dst;
    const int4* src4 = (const int4*)src;

    for (int b = tid; b < NBKT; b += 512) lhist[b] = 0;
    __syncthreads();
    #pragma unroll
    for (int i = 0; i < 4; i++) {
        int e4 = base4 + i * 512 + tid;
        if (e4 < NV4) {
            int4 d = dst4[e4];
            atomicAdd(&lhist[d.x >> 7], 1);
            atomicAdd(&lhist[d.y >> 7], 1);
            atomicAdd(&lhist[d.z >> 7], 1);
            atomicAdd(&lhist[d.w >> 7], 1);
        }
    }
    __syncthreads();
    // exclusive scan over 782 bucket counts: thread t owns buckets 2t,2t+1
    int i0 = tid * 2, i1 = i0 + 1;
    int c0 = (i0 < NBKT) ? lhist[i0] : 0;
    int c1 = (i1 < NBKT) ? lhist[i1] : 0;
    int v = c0 + c1;
    int lane = tid & 63, wid = tid >> 6;
    int sc = v;
    #pragma unroll
    for (int o = 1; o < 64; o <<= 1) {
        int t2 = __shfl_up(sc, o, 64);
        if (lane >= o) sc += t2;
    }
    if (lane == 63) wsum[wid] = sc;
    __syncthreads();
    int wo = 0;
    #pragma unroll
    for (int w = 0; w < 8; w++) wo += (w < wid) ? wsum[w] : 0;
    int excl = sc - v + wo;
    if (i0 < NBKT) { lstart[i0] = excl;      lcur[i0] = excl; }
    if (i1 < NBKT) { lstart[i1] = excl + c0; lcur[i1] = excl + c0; }
    for (int b = tid; b < NBKT; b += 512) {
        int c = lhist[b];
        lbase[b] = c ? atomicAdd(&gcursor[b], c) : 0;
    }
    __syncthreads();
    #pragma unroll
    for (int i = 0; i < 4; i++) {
        int e4 = base4 + i * 512 + tid;
        if (e4 < NV4) {
            int4 d = dst4[e4];
            int4 s = src4[e4];
            int p0 = atomicAdd(&lcur[d.x >> 7], 1);
            lsort[p0] = ((d.x & 127) << 17) | s.x;
            int p1 = atomicAdd(&lcur[d.y >> 7], 1);
            lsort[p1] = ((d.y & 127) << 17) | s.y;
            int p2 = atomicAdd(&lcur[d.z >> 7], 1);
            lsort[p2] = ((d.z & 127) << 17) | s.z;
            int p3 = atomicAdd(&lcur[d.w >> 7], 1);
            lsort[p3] = ((d.w & 127) << 17) | s.w;
        }
    }
    __syncthreads();
    int grp = tid >> 4, gl = tid & 15;
    for (int b = grp; b < NBKT; b += 32) {
        int st = lstart[b], c = lhist[b], gb = lbase[b];
        int lim = (b + 1) * CAP;
        for (int k = gl; k < c; k += 16) {
            int pos = gb + k;
            if (pos < lim)   // capacity guard (P ~ 5e-6 total)
                buf[pos] = lsort[st + k];
        }
    }
}

// ---- part2: per-bucket fine sort in LDS; int4 loads, shuffle scan --------
__global__ __launch_bounds__(512) void part2_kernel(const int* __restrict__ gcursor,
                                                    int* __restrict__ buf,
                                                    int* __restrict__ nodeinfo,
                                                    float* __restrict__ dinv) {
    __shared__ int lcnt[128], lcur[128];
    __shared__ int w0sum;
    __shared__ int lsort[CAP];
    int b = blockIdx.x, tid = threadIdx.x;
    int base = b * CAP;                 // CAP%4==0 -> 16B aligned
    int end = gcursor[b];
    int count = end - base;
    int cnt4 = count >> 2;
    const int4* buf4 = (const int4*)(buf + base);
    if (tid < 128) lcnt[tid] = 0;
    __syncthreads();
    for (int i = tid; i < cnt4; i += 512) {
        int4 w = buf4[i];
        atomicAdd(&lcnt[w.x >> 17], 1);
        atomicAdd(&lcnt[w.y >> 17], 1);
        atomicAdd(&lcnt[w.z >> 17], 1);
        atomicAdd(&lcnt[w.w >> 17], 1);
    }
    for (int i = (cnt4 << 2) + tid; i < count; i += 512)
        atomicAdd(&lcnt[buf[base + i] >> 17], 1);
    __syncthreads();
    // shuffle scan over 128 counters (waves 0 and 1)
    if (tid < 128) {
        int v = lcnt[tid];
        int lane = tid & 63;
        int sc = v;
        #pragma unroll
        for (int o = 1; o < 64; o <<= 1) {
            int t2 = __shfl_up(sc, o, 64);
            if (lane >= o) sc += t2;
        }
        if (tid == 63) w0sum = sc;
        __syncthreads();
        int incl = sc + ((tid >= 64) ? w0sum : 0);
        int excl = incl - v;
        lcur[tid] = excl;
        int n = b * 128 + tid;
        if (n < N_NODES) {
            nodeinfo[n] = (v << 23) | (base + excl);
            dinv[n] = rsqrtf((float)v + 1.0f);  // +1 self-loop
        }
    } else {
        __syncthreads();
    }
    __syncthreads();
    for (int i = tid; i < cnt4; i += 512) {
        int4 w = buf4[i];
        int p0 = atomicAdd(&lcur[w.x >> 17], 1); lsort[p0] = w.x & 0x1FFFF;
        int p1 = atomicAdd(&lcur[w.y >> 17], 1); lsort[p1] = w.y & 0x1FFFF;
        int p2 = atomicAdd(&lcur[w.z >> 17], 1); lsort[p2] = w.z & 0x1FFFF;
        int p3 = atomicAdd(&lcur[w.w >> 17], 1); lsort[p3] = w.w & 0x1FFFF;
    }
    for (int i = (cnt4 << 2) + tid; i < count; i += 512) {
        int w = buf[base + i];
        int pos = atomicAdd(&lcur[w >> 17], 1);
        lsort[pos] = w & 0x1FFFF;
    }
    __syncthreads();
    int4* bufw4 = (int4*)(buf + base);
    const int4* lsort4 = (const int4*)lsort;
    for (int i = tid; i < cnt4; i += 512) bufw4[i] = lsort4[i];
    for (int i = (cnt4 << 2) + tid; i < count; i += 512) buf[base + i] = lsort[i];
}

// ---- LayerNorm + W1 via MFMA: 64 nodes per 256-thread block --------------
#define XSTR 136
__global__ __launch_bounds__(256) void ln_w1_kernel(const float* __restrict__ x,
                             const float* __restrict__ gamma,
                             const float* __restrict__ beta,
                             const float* __restrict__ W1,
                             const float* __restrict__ dinv,
                             __half* __restrict__ g1) {
    __shared__ __align__(16) _Float16 xnh[64 * XSTR];   // 17408 B
    __shared__ __align__(16) _Float16 w1t[16 * XSTR];   //  4352 B
    int tid = threadIdx.x;
    int r = tid >> 2, q = tid & 3;
    int node = blockIdx.x * 64 + r;

    // stage W1^T as f16: thread (n=tid&15, kb=tid>>4) covers 8 k's
    {
        int n = tid & 15, kb = tid >> 4;
        f16x8 wv;
        #pragma unroll
        for (int j = 0; j < 8; j++)
            wv[j] = (_Float16)W1[(kb * 8 + j) * 16 + n];
        *(f16x8*)&w1t[n * XSTR + kb * 8] = wv;
    }

    // load quarter-row, LN stats over 4 lanes
    bool valid = node < N_NODES;
    const float4* xr4 = (const float4*)(x + (size_t)node * 128 + q * 32);
    float4 xv[8];
    #pragma unroll
    for (int j = 0; j < 8; j++)
        xv[j] = valid ? xr4[j] : make_float4(0.f, 0.f, 0.f, 0.f);
    float s1 = 0.f, s2 = 0.f;
    #pragma unroll
    for (int j = 0; j < 8; j++) {
        s1 += xv[j].x + xv[j].y + xv[j].z + xv[j].w;
        s2 += xv[j].x * xv[j].x + xv[j].y * xv[j].y
            + xv[j].z * xv[j].z + xv[j].w * xv[j].w;
    }
    s1 += __shfl_xor(s1, 1, 64); s1 += __shfl_xor(s1, 2, 64);
    s2 += __shfl_xor(s2, 1, 64); s2 += __shfl_xor(s2, 2, 64);
    float mu = s1 * (1.0f / 128.0f);
    float var = s2 * (1.0f / 128.0f) - mu * mu;
    float rstd = rsqrtf(var + 1e-5f);

    const float4* g4 = (const float4*)(gamma + q * 32);
    const float4* b4 = (const float4*)(beta + q * 32);
    #pragma unroll
    for (int t = 0; t < 4; t++) {
        f16x8 h;
        #pragma unroll
        for (int u = 0; u < 2; u++) {
            int j = t * 2 + u;
            float4 gv = g4[j], bv = b4[j];
            h[u * 4 + 0] = (_Float16)((xv[j].x - mu) * rstd * gv.x + bv.x);
            h[u * 4 + 1] = (_Float16)((xv[j].y - mu) * rstd * gv.y + bv.y);
            h[u * 4 + 2] = (_Float16)((xv[j].z - mu) * rstd * gv.z + bv.z);
            h[u * 4 + 3] = (_Float16)((xv[j].w - mu) * rstd * gv.w + bv.w);
        }
        *(f16x8*)&xnh[r * XSTR + q * 32 + t * 8] = h;
    }
    __syncthreads();

    // MFMA phase: wave w -> rows 16w..16w+15
    int l = tid & 63, w = tid >> 6;
    int am = l & 15, ak = l >> 4;   // A row / k-subgroup
    const _Float16* abase = &xnh[(w * 16 + am) * XSTR + ak * 8];
    const _Float16* bbase = &w1t[am * XSTR + ak * 8];
    f32x4 acc = {0.f, 0.f, 0.f, 0.f};
    #pragma unroll
    for (int kk = 0; kk < 4; kk++) {
        f16x8 av = *(const f16x8*)(abase + kk * 32);
        f16x8 bv = *(const f16x8*)(bbase + kk * 32);
        acc = __builtin_amdgcn_mfma_f32_16x16x32_f16(av, bv, acc, 0, 0, 0);
    }
    _Float16* g1h = (_Float16*)g1;
    #pragma unroll
    for (int reg = 0; reg < 4; reg++) {
        int row = w * 16 + ak * 4 + reg;            // C: row=(l>>4)*4+reg
        int nn = blockIdx.x * 64 + row;
        if (nn < N_NODES)
            g1h[nn * 16 + am] = (_Float16)(acc[reg] * dinv[nn]);  // col=l&15
    }
}

// ---- pull conv1 + fused finalize1: 4 nodes/wave, 2x16B gather per row ----
// lane layout in 16-lane group: c2 = l&1 (16B half-row), e8 = l>>1 (8 edge
// slots). Each row is fetched by 2 lanes x dwordx4 (guaranteed <=2 L1
// requests/row vs 4x8B quad-merge in R5). 3-stage halving butterfly leaves
// lane l holding component cc = bitrev4(l); W2 broadcast uses compile-time
// bit-reversed source lanes.
__global__ __launch_bounds__(256) void pull1_kernel(const int* __restrict__ nodeinfo,
                             const int* __restrict__ sorted_src,
                             const __half* __restrict__ g1,
                             const float* __restrict__ dinv,
                             const float* __restrict__ b1,
                             const float* __restrict__ W2,
                             const uint64_t* __restrict__ m1,
                             __half* __restrict__ g2) {
    __shared__ float sW2[HIDDEN * HIDDEN];
    sW2[threadIdx.x] = W2[threadIdx.x];     // 256 threads == 256 elems
    __syncthreads();
    int n = blockIdx.x * 16 + (threadIdx.x >> 4);  // grid*16 == N_NODES
    int l = threadIdx.x & 15;
    int c2 = l & 1, e8 = l >> 1;
    const _Float16* gt = (const _Float16*)g1;
    int info = nodeinfo[n];
    int start = info & 0x7FFFFF;
    int deg = (int)((unsigned)info >> 23);

    float acc[8] = {0.f,0.f,0.f,0.f,0.f,0.f,0.f,0.f};
    float acc2[8] = {0.f,0.f,0.f,0.f,0.f,0.f,0.f,0.f};
    if (e8 == 0) {                                  // self row, lanes 0,1
        f16x8 sv = *(const f16x8*)(gt + (uint32_t)n * 16 + c2 * 8);
        #pragma unroll
        for (int j = 0; j < 8; j++) acc[j] = (float)sv[j];
    }
    int km = (deg > 0) ? deg - 1 : 0;
    for (int kb = 0; kb < deg; kb += 16) {
        int k0 = kb + e8, k1 = kb + 8 + e8;
        int s0 = sorted_src[start + min(k0, km)];
        int s1 = sorted_src[start + min(k1, km)];
        if (k0 < deg) {
            f16x8 gv = *(const f16x8*)(gt + (uint32_t)s0 * 16 + c2 * 8);
            #pragma unroll
            for (int j = 0; j < 8; j++) acc[j] += (float)gv[j];
        }
        if (k1 < deg) {
            f16x8 gv = *(const f16x8*)(gt + (uint32_t)s1 * 16 + c2 * 8);
            #pragma unroll
            for (int j = 0; j < 8; j++) acc2[j] += (float)gv[j];
        }
    }
    #pragma unroll
    for (int j = 0; j < 8; j++) acc[j] += acc2[j];
    // halving butterfly over e8: xor 2, 4, 8
    float h4[4];
    {
        int sel = e8 & 1;
        #pragma unroll
        for (int j = 0; j < 4; j++) {
            float mine = sel ? acc[j + 4] : acc[j];
            float give = sel ? acc[j] : acc[j + 4];
            h4[j] = mine + __shfl_xor(give, 2, 64);
        }
    }
    float h2[2];
    {
        int sel = (e8 >> 1) & 1;
        #pragma unroll
        for (int j = 0; j < 2; j++) {
            float mine = sel ? h4[j + 2] : h4[j];
            float give = sel ? h4[j] : h4[j + 2];
            h2[j] = mine + __shfl_xor(give, 4, 64);
        }
    }
    float hv;
    {
        int sel = (e8 >> 2) & 1;
        float mine = sel ? h2[1] : h2[0];
        float give = sel ? h2[0] : h2[1];
        hv = mine + __shfl_xor(give, 8, 64);
    }
    // lane l holds component cc
    int cc = c2 * 8 + (e8 & 1) * 4 + ((e8 >> 1) & 1) * 2 + ((e8 >> 2) & 1);
    float di = dinv[n];
    uint32_t mbits = (uint32_t)(m1[n >> 2] >> ((n & 3) * 16));
    float hd = ((mbits >> cc) & 1)
             ? fmaxf(di * hv + b1[cc], 0.f) * (1.0f / 0.7f) : 0.f;
    // h @ W2: broadcast hd from bit-reversed lane per i (compile-time)
    int grpbase = threadIdx.x & 48;
    int c = l & 3;
    float4 o4 = make_float4(0.f, 0.f, 0.f, 0.f);
    #pragma unroll
    for (int i = 0; i < 16; i++) {
        int srcl = grpbase + (((i >> 3) & 1) | (((i >> 2) & 1) << 1) |
                              (((i >> 1) & 1) << 2) | ((i & 1) << 3));
        float hi = __shfl(hd, srcl, 64);
        const float4 w = *(const float4*)&sW2[i * HIDDEN + c * 4];
        o4.x += hi * w.x; o4.y += hi * w.y; o4.z += hi * w.z; o4.w += hi * w.w;
    }
    if (l < 4) {
        __half2 p0 = __floats2half2_rn(o4.x * di, o4.y * di);
        __half2 p1 = __floats2half2_rn(o4.z * di, o4.w * di);
        uint2 u;
        u.x = *(uint32_t*)&p0; u.y = *(uint32_t*)&p1;
        *(uint2*)((__half*)g2 + (uint32_t)n * 16 + c * 4) = u;
    }
}

// ---- pull conv2 + fused finalize2: same layout, fp32 output --------------
__global__ __launch_bounds__(256) void pull2_kernel(const int* __restrict__ nodeinfo,
                             const int* __restrict__ sorted_src,
                             const __half* __restrict__ g2,
                             const float* __restrict__ dinv,
                             const float* __restrict__ b2,
                             const uint64_t* __restrict__ m2,
                             float* __restrict__ out) {
    int n = blockIdx.x * 16 + (threadIdx.x >> 4);
    int l = threadIdx.x & 15;
    int c2 = l & 1, e8 = l >> 1;
    const _Float16* gt = (const _Float16*)g2;
    int info = nodeinfo[n];
    int start = info & 0x7FFFFF;
    int deg = (int)((unsigned)info >> 23);

    float acc[8] = {0.f,0.f,0.f,0.f,0.f,0.f,0.f,0.f};
    float acc2[8] = {0.f,0.f,0.f,0.f,0.f,0.f,0.f,0.f};
    if (e8 == 0) {                                  // self row
        f16x8 sv = *(const f16x8*)(gt + (uint32_t)n * 16 + c2 * 8);
        #pragma unroll
        for (int j = 0; j < 8; j++) acc[j] = (float)sv[j];
    }
    int km = (deg > 0) ? deg - 1 : 0;
    for (int kb = 0; kb < deg; kb += 16) {
        int k0 = kb + e8, k1 = kb + 8 + e8;
        int s0 = sorted_src[start + min(k0, km)];
        int s1 = sorted_src[start + min(k1, km)];
        if (k0 < deg) {
            f16x8 gv = *(const f16x8*)(gt + (uint32_t)s0 * 16 + c2 * 8);
            #pragma unroll
            for (int j = 0; j < 8; j++) acc[j] += (float)gv[j];
        }
        if (k1 < deg) {
            f16x8 gv = *(const f16x8*)(gt + (uint32_t)s1 * 16 + c2 * 8);
            #pragma unroll
            for (int j = 0; j < 8; j++) acc2[j] += (float)gv[j];
        }
    }
    #pragma unroll
    for (int j = 0; j < 8; j++) acc[j] += acc2[j];
    float h4[4];
    {
        int sel = e8 & 1;
        #pragma unroll
        for (int j = 0; j < 4; j++) {
            float mine = sel ? acc[j + 4] : acc[j];
            float give = sel ? acc[j] : acc[j + 4];
            h4[j] = mine + __shfl_xor(give, 2, 64);
        }
    }
    float h2[2];
    {
        int sel = (e8 >> 1) & 1;
        #pragma unroll
        for (int j = 0; j < 2; j++) {
            float mine = sel ? h4[j + 2] : h4[j];
            float give = sel ? h4[j] : h4[j + 2];
            h2[j] = mine + __shfl_xor(give, 4, 64);
        }
    }
    float hv;
    {
        int sel = (e8 >> 2) & 1;
        float mine = sel ? h2[1] : h2[0];
        float give = sel ? h2[0] : h2[1];
        hv = mine + __shfl_xor(give, 8, 64);
    }
    int cc = c2 * 8 + (e8 & 1) * 4 + ((e8 >> 1) & 1) * 2 + ((e8 >> 2) & 1);
    float di = dinv[n];
    uint32_t mbits = (uint32_t)(m2[n >> 2] >> ((n & 3) * 16));
    float r = ((mbits >> cc) & 1)
            ? fmaxf(di * hv + b2[cc], 0.f) * (1.0f / 0.7f) : 0.f;
    out[(uint32_t)n * 16 + cc] = r;   // 16 lanes cover one 64B line
}

extern "C" void kernel_launch(void* const* d_in, const int* in_sizes, int n_in,
                              void* d_out, int out_size, void* d_ws, size_t ws_size,
                              hipStream_t stream) {
    const float* x     = (const float*)d_in[0];
    const int*   ei    = (const int*)d_in[1];
    const float* gamma = (const float*)d_in[2];
    const float* beta  = (const float*)d_in[3];
    const float* W1    = (const float*)d_in[4];
    const float* b1    = (const float*)d_in[5];
    const float* W2    = (const float*)d_in[6];
    const float* b2    = (const float*)d_in[7];
    float* out = (float*)d_out;
    const int* src = ei;
    const int* dst = ei + N_EDGES;

    uint32_t dk1_0, dk1_1, dk2_0, dk2_1;
    threefry2x32(0u, 42u, 0u, 0u, dk1_0, dk1_1);
    threefry2x32(0u, 42u, 0u, 1u, dk2_0, dk2_1);

    // ws layout (4B elems): gcursor[1024] | nodeinfo[100k] | dinv[100k] |
    // buf[NBKT*CAP] | g1h[1.6M half = 800k int] | g2h[800k int] |
    // m1[25k ull] | m2[25k ull]  (~36MB)
    int*      gcursor  = (int*)d_ws;
    int*      nodeinfo = gcursor + 1024;
    float*    dinv     = (float*)(nodeinfo + N_NODES);
    int*      buf      = (int*)(dinv + N_NODES);
    __half*   g1h      = (__half*)(buf + (size_t)NBKT * CAP);
    __half*   g2h      = g1h + (size_t)N_NODES * HIDDEN;
    uint64_t* m1       = (uint64_t*)(g2h + (size_t)N_NODES * HIDDEN);
    uint64_t* m2       = m1 + (NMASK >> 6);

    const int NB_LN = (N_NODES + 63) / 64;             // 1563 (64 nodes/block)
    const int NB_PULL = N_NODES / 16;                  // 6250 (pull: 16 nodes/block)
    const int NB_P1 = (N_EDGES + P1_EPB - 1) / P1_EPB; // 782

    initcur_kernel<<<1, 1024, 0, stream>>>(gcursor);
    dropmask_kernel<<<(2 * NMASK) / 256, 256, 0, stream>>>(m1, m2,
                                                           dk1_0, dk1_1,
                                                           dk2_0, dk2_1);
    part1_kernel<<<NB_P1, 512, 0, stream>>>(src, dst, gcursor, buf);
    part2_kernel<<<NBKT, 512, 0, stream>>>(gcursor, buf, nodeinfo, dinv);
    ln_w1_kernel<<<NB_LN, 256, 0, stream>>>(x, gamma, beta, W1, dinv, g1h);
    pull1_kernel<<<NB_PULL, 256, 0, stream>>>(nodeinfo, buf, g1h,
                                              dinv, b1, W2, m1, g2h);
    pull2_kernel<<<NB_PULL, 256, 0, stream>>>(nodeinfo, buf, g2h,
                                              dinv, b2, m2, out);
}

// Round 8
// 283.363 us; speedup vs baseline: 1.5107x; 1.1139x over previous
//
#include <hip/hip_runtime.h>
#include <hip/hip_fp16.h>
#include <stdint.h>
#include <stddef.h>

#define N_NODES 100000
#define N_EDGES 6400000
#define HIDDEN 16
#define NBKT 782          /* ceil(100000/128) coarse buckets of 128 nodes */
#define CAP 8704          /* bucket region capacity: mean 8184 + 5.7 sigma */
#define P1_EPB 8192       /* edges per part1 block */
#define NMASK 1600000     /* N_NODES*HIDDEN */

typedef _Float16 f16x8 __attribute__((ext_vector_type(8)));
typedef _Float16 f16x4 __attribute__((ext_vector_type(4)));
typedef float f32x4 __attribute__((ext_vector_type(4)));

__host__ __device__ inline uint32_t rotl32(uint32_t x, int n) {
    return (x << n) | (x >> (32 - n));
}

// Exact JAX threefry2x32 (20 rounds)
__host__ __device__ inline void threefry2x32(uint32_t k0, uint32_t k1,
                                             uint32_t x0, uint32_t x1,
                                             uint32_t& o0, uint32_t& o1) {
    uint32_t k2 = k0 ^ k1 ^ 0x1BD11BDAu;
    x0 += k0; x1 += k1;
    x0 += x1; x1 = rotl32(x1, 13); x1 ^= x0;
    x0 += x1; x1 = rotl32(x1, 15); x1 ^= x0;
    x0 += x1; x1 = rotl32(x1, 26); x1 ^= x0;
    x0 += x1; x1 = rotl32(x1,  6); x1 ^= x0;
    x0 += k1; x1 += k2 + 1u;
    x0 += x1; x1 = rotl32(x1, 17); x1 ^= x0;
    x0 += x1; x1 = rotl32(x1, 29); x1 ^= x0;
    x0 += x1; x1 = rotl32(x1, 16); x1 ^= x0;
    x0 += x1; x1 = rotl32(x1, 24); x1 ^= x0;
    x0 += k2; x1 += k0 + 2u;
    x0 += x1; x1 = rotl32(x1, 13); x1 ^= x0;
    x0 += x1; x1 = rotl32(x1, 15); x1 ^= x0;
    x0 += x1; x1 = rotl32(x1, 26); x1 ^= x0;
    x0 += x1; x1 = rotl32(x1,  6); x1 ^= x0;
    x0 += k0; x1 += k1 + 3u;
    x0 += x1; x1 = rotl32(x1, 17); x1 ^= x0;
    x0 += x1; x1 = rotl32(x1, 29); x1 ^= x0;
    x0 += x1; x1 = rotl32(x1, 16); x1 ^= x0;
    x0 += x1; x1 = rotl32(x1, 24); x1 ^= x0;
    x0 += k1; x1 += k2 + 4u;
    x0 += x1; x1 = rotl32(x1, 13); x1 ^= x0;
    x0 += x1; x1 = rotl32(x1, 15); x1 ^= x0;
    x0 += x1; x1 = rotl32(x1, 26); x1 ^= x0;
    x0 += x1; x1 = rotl32(x1,  6); x1 ^= x0;
    x0 += k2; x1 += k0 + 5u;
    o0 = x0; o1 = x1;
}

// ---- dropout keep-bit masks, 1 threefry eval per lane, ballot-packed -----
__global__ __launch_bounds__(256) void dropmask_kernel(uint64_t* __restrict__ m1,
                                                       uint64_t* __restrict__ m2,
                                                       uint32_t k10, uint32_t k11,
                                                       uint32_t k20, uint32_t k21) {
    int g = blockIdx.x * blockDim.x + threadIdx.x;   // [0, 2*NMASK)
    int lane = threadIdx.x & 63;
    bool first = g < NMASK;
    uint32_t j = first ? (uint32_t)g : (uint32_t)(g - NMASK);
    uint32_t a, b;
    threefry2x32(first ? k10 : k20, first ? k11 : k21, 0u, j, a, b);
    uint32_t bits = a ^ b;
    float u = __uint_as_float((bits >> 9) | 0x3F800000u) - 1.0f;
    unsigned long long m = __ballot(u >= 0.3f);
    if (lane == 0) {
        int gw = g >> 6;
        if (first) m1[gw] = m;
        else       m2[gw - (NMASK >> 6)] = m;
    }
}

// ---- gcursor[b] = b*CAP (fixed-capacity bucket regions, no scan) ---------
__global__ void initcur_kernel(int* __restrict__ gcursor) {
    int b = threadIdx.x;
    if (b < NBKT) gcursor[b] = b * CAP;
}

// ---- partition pass 1: LDS counting sort, int4 loads, shuffle scan -------
// lsort staging is load-bearing: it turns 6.4M scattered 4B stores into
// contiguous ~42B runs (R3 measured 172MB writes without it vs 43MB with).
__global__ __launch_bounds__(512) void part1_kernel(const int* __restrict__ src,
                                                    const int* __restrict__ dst,
                                                    int* __restrict__ gcursor,
                                                    int* __restrict__ buf) {
    __shared__ int lhist[NBKT], lbase[NBKT], lstart[NBKT], lcur[NBKT];
    __shared__ int wsum[8];
    __shared__ int lsort[P1_EPB];
    int tid = threadIdx.x;
    const int NV4 = N_EDGES >> 2;                 // 1.6M int4 groups
    int base4 = blockIdx.x * (P1_EPB >> 2);       // 2048 int4 per block
    const int4* dst4 = (const int4*)dst;
    const int4* src4 = (const int4*)src;

    for (int b = tid; b < NBKT; b += 512) lhist[b] = 0;
    __syncthreads();
    #pragma unroll
    for (int i = 0; i < 4; i++) {
        int e4 = base4 + i * 512 + tid;
        if (e4 < NV4) {
            int4 d = dst4[e4];
            atomicAdd(&lhist[d.x >> 7], 1);
            atomicAdd(&lhist[d.y >> 7], 1);
            atomicAdd(&lhist[d.z >> 7], 1);
            atomicAdd(&lhist[d.w >> 7], 1);
        }
    }
    __syncthreads();
    // exclusive scan over 782 bucket counts: thread t owns buckets 2t,2t+1
    int i0 = tid * 2, i1 = i0 + 1;
    int c0 = (i0 < NBKT) ? lhist[i0] : 0;
    int c1 = (i1 < NBKT) ? lhist[i1] : 0;
    int v = c0 + c1;
    int lane = tid & 63, wid = tid >> 6;
    int sc = v;
    #pragma unroll
    for (int o = 1; o < 64; o <<= 1) {
        int t2 = __shfl_up(sc, o, 64);
        if (lane >= o) sc += t2;
    }
    if (lane == 63) wsum[wid] = sc;
    __syncthreads();
    int wo = 0;
    #pragma unroll
    for (int w = 0; w < 8; w++) wo += (w < wid) ? wsum[w] : 0;
    int excl = sc - v + wo;
    if (i0 < NBKT) { lstart[i0] = excl;      lcur[i0] = excl; }
    if (i1 < NBKT) { lstart[i1] = excl + c0; lcur[i1] = excl + c0; }
    for (int b = tid; b < NBKT; b += 512) {
        int c = lhist[b];
        lbase[b] = c ? atomicAdd(&gcursor[b], c) : 0;
    }
    __syncthreads();
    #pragma unroll
    for (int i = 0; i < 4; i++) {
        int e4 = base4 + i * 512 + tid;
        if (e4 < NV4) {
            int4 d = dst4[e4];
            int4 s = src4[e4];
            int p0 = atomicAdd(&lcur[d.x >> 7], 1);
            lsort[p0] = ((d.x & 127) << 17) | s.x;
            int p1 = atomicAdd(&lcur[d.y >> 7], 1);
            lsort[p1] = ((d.y & 127) << 17) | s.y;
            int p2 = atomicAdd(&lcur[d.z >> 7], 1);
            lsort[p2] = ((d.z & 127) << 17) | s.z;
            int p3 = atomicAdd(&lcur[d.w >> 7], 1);
            lsort[p3] = ((d.w & 127) << 17) | s.w;
        }
    }
    __syncthreads();
    int grp = tid >> 4, gl = tid & 15;
    for (int b = grp; b < NBKT; b += 32) {
        int st = lstart[b], c = lhist[b], gb = lbase[b];
        int lim = (b + 1) * CAP;
        for (int k = gl; k < c; k += 16) {
            int pos = gb + k;
            if (pos < lim)   // capacity guard (P ~ 5e-6 total)
                buf[pos] = lsort[st + k];
        }
    }
}

// ---- part2: per-bucket fine sort in LDS; int4 loads, shuffle scan --------
__global__ __launch_bounds__(512) void part2_kernel(const int* __restrict__ gcursor,
                                                    int* __restrict__ buf,
                                                    int* __restrict__ nodeinfo,
                                                    float* __restrict__ dinv) {
    __shared__ int lcnt[128], lcur[128];
    __shared__ int w0sum;
    __shared__ int lsort[CAP];
    int b = blockIdx.x, tid = threadIdx.x;
    int base = b * CAP;                 // CAP%4==0 -> 16B aligned
    int end = gcursor[b];
    int count = end - base;
    int cnt4 = count >> 2;
    const int4* buf4 = (const int4*)(buf + base);
    if (tid < 128) lcnt[tid] = 0;
    __syncthreads();
    for (int i = tid; i < cnt4; i += 512) {
        int4 w = buf4[i];
        atomicAdd(&lcnt[w.x >> 17], 1);
        atomicAdd(&lcnt[w.y >> 17], 1);
        atomicAdd(&lcnt[w.z >> 17], 1);
        atomicAdd(&lcnt[w.w >> 17], 1);
    }
    for (int i = (cnt4 << 2) + tid; i < count; i += 512)
        atomicAdd(&lcnt[buf[base + i] >> 17], 1);
    __syncthreads();
    // shuffle scan over 128 counters (waves 0 and 1)
    if (tid < 128) {
        int v = lcnt[tid];
        int lane = tid & 63;
        int sc = v;
        #pragma unroll
        for (int o = 1; o < 64; o <<= 1) {
            int t2 = __shfl_up(sc, o, 64);
            if (lane >= o) sc += t2;
        }
        if (tid == 63) w0sum = sc;
        __syncthreads();
        int incl = sc + ((tid >= 64) ? w0sum : 0);
        int excl = incl - v;
        lcur[tid] = excl;
        int n = b * 128 + tid;
        if (n < N_NODES) {
            nodeinfo[n] = (v << 23) | (base + excl);
            dinv[n] = rsqrtf((float)v + 1.0f);  // +1 self-loop
        }
    } else {
        __syncthreads();
    }
    __syncthreads();
    for (int i = tid; i < cnt4; i += 512) {
        int4 w = buf4[i];
        int p0 = atomicAdd(&lcur[w.x >> 17], 1); lsort[p0] = w.x & 0x1FFFF;
        int p1 = atomicAdd(&lcur[w.y >> 17], 1); lsort[p1] = w.y & 0x1FFFF;
        int p2 = atomicAdd(&lcur[w.z >> 17], 1); lsort[p2] = w.z & 0x1FFFF;
        int p3 = atomicAdd(&lcur[w.w >> 17], 1); lsort[p3] = w.w & 0x1FFFF;
    }
    for (int i = (cnt4 << 2) + tid; i < count; i += 512) {
        int w = buf[base + i];
        int pos = atomicAdd(&lcur[w >> 17], 1);
        lsort[pos] = w & 0x1FFFF;
    }
    __syncthreads();
    int4* bufw4 = (int4*)(buf + base);
    const int4* lsort4 = (const int4*)lsort;
    for (int i = tid; i < cnt4; i += 512) bufw4[i] = lsort4[i];
    for (int i = (cnt4 << 2) + tid; i < count; i += 512) buf[base + i] = lsort[i];
}

// ---- LayerNorm + W1 via MFMA: 64 nodes per 256-thread block --------------
// Coalesced one-touch x load (slot-major): thread t slot j holds float4
// idx = j*256+t of the block's 64x128 tile -> each load instr covers 4KB
// contiguous (R6 fix: the quarter-row mapping fetched 108MB = 2.1x input
// at 2TB/s scattered-16B throughput). Row structure: slot j of thread t
// holds row 8j+(t>>5), col (t&31)*4 -> LN stats = 5-stage 32-lane shfl_xor
// butterfly per slot, all in-register. f16 xn -> LDS [64][136] -> MFMA.
#define XSTR 136
__global__ __launch_bounds__(256) void ln_w1_kernel(const float* __restrict__ x,
                             const float* __restrict__ gamma,
                             const float* __restrict__ beta,
                             const float* __restrict__ W1,
                             const float* __restrict__ dinv,
                             __half* __restrict__ g1) {
    __shared__ __align__(16) _Float16 xnh[64 * XSTR];   // 17408 B
    __shared__ __align__(16) _Float16 w1t[16 * XSTR];   //  4352 B
    int tid = threadIdx.x;

    // stage W1^T as f16: thread (n=tid&15, kb=tid>>4) covers 8 k's
    {
        int n = tid & 15, kb = tid >> 4;
        f16x8 wv;
        #pragma unroll
        for (int j = 0; j < 8; j++)
            wv[j] = (_Float16)W1[(kb * 8 + j) * 16 + n];
        *(f16x8*)&w1t[n * XSTR + kb * 8] = wv;
    }

    // coalesced loads: 8 x (256 lanes x 16B) = the full 32KB tile, one touch
    const float4* xt = (const float4*)x;
    size_t base4 = (size_t)blockIdx.x * 2048;
    const size_t NF4 = (size_t)N_NODES * 32;
    float4 v[8];
    #pragma unroll
    for (int j = 0; j < 8; j++) {
        size_t idx = base4 + (size_t)j * 256 + tid;
        v[j] = (idx < NF4) ? xt[idx] : make_float4(0.f, 0.f, 0.f, 0.f);
    }
    int col = tid & 31;            // float4 column within row
    int sub = tid >> 5;            // row sub-index within slot
    float4 gv = ((const float4*)gamma)[col];
    float4 bv = ((const float4*)beta)[col];
    #pragma unroll
    for (int j = 0; j < 8; j++) {
        float s1 = v[j].x + v[j].y + v[j].z + v[j].w;
        float s2 = v[j].x * v[j].x + v[j].y * v[j].y
                 + v[j].z * v[j].z + v[j].w * v[j].w;
        #pragma unroll
        for (int o = 1; o < 32; o <<= 1) {      // 32-lane row butterfly
            s1 += __shfl_xor(s1, o, 64);
            s2 += __shfl_xor(s2, o, 64);
        }
        float mu = s1 * (1.0f / 128.0f);
        float var = s2 * (1.0f / 128.0f) - mu * mu;
        float rstd = rsqrtf(var + 1e-5f);
        int row = j * 8 + sub;
        f16x4 h;
        h[0] = (_Float16)((v[j].x - mu) * rstd * gv.x + bv.x);
        h[1] = (_Float16)((v[j].y - mu) * rstd * gv.y + bv.y);
        h[2] = (_Float16)((v[j].z - mu) * rstd * gv.z + bv.z);
        h[3] = (_Float16)((v[j].w - mu) * rstd * gv.w + bv.w);
        *(f16x4*)&xnh[row * XSTR + col * 4] = h;
    }
    __syncthreads();

    // MFMA phase: wave w -> rows 16w..16w+15
    int l = tid & 63, w = tid >> 6;
    int am = l & 15, ak = l >> 4;   // A row / k-subgroup
    const _Float16* abase = &xnh[(w * 16 + am) * XSTR + ak * 8];
    const _Float16* bbase = &w1t[am * XSTR + ak * 8];
    f32x4 acc = {0.f, 0.f, 0.f, 0.f};
    #pragma unroll
    for (int kk = 0; kk < 4; kk++) {
        f16x8 av = *(const f16x8*)(abase + kk * 32);
        f16x8 bv2 = *(const f16x8*)(bbase + kk * 32);
        acc = __builtin_amdgcn_mfma_f32_16x16x32_f16(av, bv2, acc, 0, 0, 0);
    }
    _Float16* g1h = (_Float16*)g1;
    #pragma unroll
    for (int reg = 0; reg < 4; reg++) {
        int row = w * 16 + ak * 4 + reg;            // C: row=(l>>4)*4+reg
        int nn = blockIdx.x * 64 + row;
        if (nn < N_NODES)
            g1h[nn * 16 + am] = (_Float16)(acc[reg] * dinv[nn]);  // col=l&15
    }
}

// ---- pull conv1 + fused finalize1: 4 nodes/wave, 2x16B gather per row ----
__global__ __launch_bounds__(256) void pull1_kernel(const int* __restrict__ nodeinfo,
                             const int* __restrict__ sorted_src,
                             const __half* __restrict__ g1,
                             const float* __restrict__ dinv,
                             const float* __restrict__ b1,
                             const float* __restrict__ W2,
                             const uint64_t* __restrict__ m1,
                             __half* __restrict__ g2) {
    __shared__ float sW2[HIDDEN * HIDDEN];
    sW2[threadIdx.x] = W2[threadIdx.x];     // 256 threads == 256 elems
    __syncthreads();
    int n = blockIdx.x * 16 + (threadIdx.x >> 4);  // grid*16 == N_NODES
    int l = threadIdx.x & 15;
    int c2 = l & 1, e8 = l >> 1;
    const _Float16* gt = (const _Float16*)g1;
    int info = nodeinfo[n];
    int start = info & 0x7FFFFF;
    int deg = (int)((unsigned)info >> 23);

    float acc[8] = {0.f,0.f,0.f,0.f,0.f,0.f,0.f,0.f};
    float acc2[8] = {0.f,0.f,0.f,0.f,0.f,0.f,0.f,0.f};
    if (e8 == 0) {                                  // self row, lanes 0,1
        f16x8 sv = *(const f16x8*)(gt + (uint32_t)n * 16 + c2 * 8);
        #pragma unroll
        for (int j = 0; j < 8; j++) acc[j] = (float)sv[j];
    }
    int km = (deg > 0) ? deg - 1 : 0;
    for (int kb = 0; kb < deg; kb += 16) {
        int k0 = kb + e8, k1 = kb + 8 + e8;
        int s0 = sorted_src[start + min(k0, km)];
        int s1 = sorted_src[start + min(k1, km)];
        if (k0 < deg) {
            f16x8 gv = *(const f16x8*)(gt + (uint32_t)s0 * 16 + c2 * 8);
            #pragma unroll
            for (int j = 0; j < 8; j++) acc[j] += (float)gv[j];
        }
        if (k1 < deg) {
            f16x8 gv = *(const f16x8*)(gt + (uint32_t)s1 * 16 + c2 * 8);
            #pragma unroll
            for (int j = 0; j < 8; j++) acc2[j] += (float)gv[j];
        }
    }
    #pragma unroll
    for (int j = 0; j < 8; j++) acc[j] += acc2[j];
    // halving butterfly over e8: xor 2, 4, 8
    float h4[4];
    {
        int sel = e8 & 1;
        #pragma unroll
        for (int j = 0; j < 4; j++) {
            float mine = sel ? acc[j + 4] : acc[j];
            float give = sel ? acc[j] : acc[j + 4];
            h4[j] = mine + __shfl_xor(give, 2, 64);
        }
    }
    float h2[2];
    {
        int sel = (e8 >> 1) & 1;
        #pragma unroll
        for (int j = 0; j < 2; j++) {
            float mine = sel ? h4[j + 2] : h4[j];
            float give = sel ? h4[j] : h4[j + 2];
            h2[j] = mine + __shfl_xor(give, 4, 64);
        }
    }
    float hv;
    {
        int sel = (e8 >> 2) & 1;
        float mine = sel ? h2[1] : h2[0];
        float give = sel ? h2[0] : h2[1];
        hv = mine + __shfl_xor(give, 8, 64);
    }
    // lane l holds component cc
    int cc = c2 * 8 + (e8 & 1) * 4 + ((e8 >> 1) & 1) * 2 + ((e8 >> 2) & 1);
    float di = dinv[n];
    uint32_t mbits = (uint32_t)(m1[n >> 2] >> ((n & 3) * 16));
    float hd = ((mbits >> cc) & 1)
             ? fmaxf(di * hv + b1[cc], 0.f) * (1.0f / 0.7f) : 0.f;
    // h @ W2: broadcast hd from bit-reversed lane per i (compile-time)
    int grpbase = threadIdx.x & 48;
    int c = l & 3;
    float4 o4 = make_float4(0.f, 0.f, 0.f, 0.f);
    #pragma unroll
    for (int i = 0; i < 16; i++) {
        int srcl = grpbase + (((i >> 3) & 1) | (((i >> 2) & 1) << 1) |
                              (((i >> 1) & 1) << 2) | ((i & 1) << 3));
        float hi = __shfl(hd, srcl, 64);
        const float4 w = *(const float4*)&sW2[i * HIDDEN + c * 4];
        o4.x += hi * w.x; o4.y += hi * w.y; o4.z += hi * w.z; o4.w += hi * w.w;
    }
    if (l < 4) {
        __half2 p0 = __floats2half2_rn(o4.x * di, o4.y * di);
        __half2 p1 = __floats2half2_rn(o4.z * di, o4.w * di);
        uint2 u;
        u.x = *(uint32_t*)&p0; u.y = *(uint32_t*)&p1;
        *(uint2*)((__half*)g2 + (uint32_t)n * 16 + c * 4) = u;
    }
}

// ---- pull conv2 + fused finalize2: same layout, fp32 output --------------
__global__ __launch_bounds__(256) void pull2_kernel(const int* __restrict__ nodeinfo,
                             const int* __restrict__ sorted_src,
                             const __half* __restrict__ g2,
                             const float* __restrict__ dinv,
                             const float* __restrict__ b2,
                             const uint64_t* __restrict__ m2,
                             float* __restrict__ out) {
    int n = blockIdx.x * 16 + (threadIdx.x >> 4);
    int l = threadIdx.x & 15;
    int c2 = l & 1, e8 = l >> 1;
    const _Float16* gt = (const _Float16*)g2;
    int info = nodeinfo[n];
    int start = info & 0x7FFFFF;
    int deg = (int)((unsigned)info >> 23);

    float acc[8] = {0.f,0.f,0.f,0.f,0.f,0.f,0.f,0.f};
    float acc2[8] = {0.f,0.f,0.f,0.f,0.f,0.f,0.f,0.f};
    if (e8 == 0) {                                  // self row
        f16x8 sv = *(const f16x8*)(gt + (uint32_t)n * 16 + c2 * 8);
        #pragma unroll
        for (int j = 0; j < 8; j++) acc[j] = (float)sv[j];
    }
    int km = (deg > 0) ? deg - 1 : 0;
    for (int kb = 0; kb < deg; kb += 16) {
        int k0 = kb + e8, k1 = kb + 8 + e8;
        int s0 = sorted_src[start + min(k0, km)];
        int s1 = sorted_src[start + min(k1, km)];
        if (k0 < deg) {
            f16x8 gv = *(const f16x8*)(gt + (uint32_t)s0 * 16 + c2 * 8);
            #pragma unroll
            for (int j = 0; j < 8; j++) acc[j] += (float)gv[j];
        }
        if (k1 < deg) {
            f16x8 gv = *(const f16x8*)(gt + (uint32_t)s1 * 16 + c2 * 8);
            #pragma unroll
            for (int j = 0; j < 8; j++) acc2[j] += (float)gv[j];
        }
    }
    #pragma unroll
    for (int j = 0; j < 8; j++) acc[j] += acc2[j];
    float h4[4];
    {
        int sel = e8 & 1;
        #pragma unroll
        for (int j = 0; j < 4; j++) {
            float mine = sel ? acc[j + 4] : acc[j];
            float give = sel ? acc[j] : acc[j + 4];
            h4[j] = mine + __shfl_xor(give, 2, 64);
        }
    }
    float h2[2];
    {
        int sel = (e8 >> 1) & 1;
        #pragma unroll
        for (int j = 0; j < 2; j++) {
            float mine = sel ? h4[j + 2] : h4[j];
            float give = sel ? h4[j] : h4[j + 2];
            h2[j] = mine + __shfl_xor(give, 4, 64);
        }
    }
    float hv;
    {
        int sel = (e8 >> 2) & 1;
        float mine = sel ? h2[1] : h2[0];
        float give = sel ? h2[0] : h2[1];
        hv = mine + __shfl_xor(give, 8, 64);
    }
    int cc = c2 * 8 + (e8 & 1) * 4 + ((e8 >> 1) & 1) * 2 + ((e8 >> 2) & 1);
    float di = dinv[n];
    uint32_t mbits = (uint32_t)(m2[n >> 2] >> ((n & 3) * 16));
    float r = ((mbits >> cc) & 1)
            ? fmaxf(di * hv + b2[cc], 0.f) * (1.0f / 0.7f) : 0.f;
    out[(uint32_t)n * 16 + cc] = r;   // 16 lanes cover one 64B line
}

extern "C" void kernel_launch(void* const* d_in, const int* in_sizes, int n_in,
                              void* d_out, int out_size, void* d_ws, size_t ws_size,
                              hipStream_t stream) {
    const float* x     = (const float*)d_in[0];
    const int*   ei    = (const int*)d_in[1];
    const float* gamma = (const float*)d_in[2];
    const float* beta  = (const float*)d_in[3];
    const float* W1    = (const float*)d_in[4];
    const float* b1    = (const float*)d_in[5];
    const float* W2    = (const float*)d_in[6];
    const float* b2    = (const float*)d_in[7];
    float* out = (float*)d_out;
    const int* src = ei;
    const int* dst = ei + N_EDGES;

    uint32_t dk1_0, dk1_1, dk2_0, dk2_1;
    threefry2x32(0u, 42u, 0u, 0u, dk1_0, dk1_1);
    threefry2x32(0u, 42u, 0u, 1u, dk2_0, dk2_1);

    // ws layout (4B elems): gcursor[1024] | nodeinfo[100k] | dinv[100k] |
    // buf[NBKT*CAP] | g1h[1.6M half = 800k int] | g2h[800k int] |
    // m1[25k ull] | m2[25k ull]  (~36MB)
    int*      gcursor  = (int*)d_ws;
    int*      nodeinfo = gcursor + 1024;
    float*    dinv     = (float*)(nodeinfo + N_NODES);
    int*      buf      = (int*)(dinv + N_NODES);
    __half*   g1h      = (__half*)(buf + (size_t)NBKT * CAP);
    __half*   g2h      = g1h + (size_t)N_NODES * HIDDEN;
    uint64_t* m1       = (uint64_t*)(g2h + (size_t)N_NODES * HIDDEN);
    uint64_t* m2       = m1 + (NMASK >> 6);

    const int NB_LN = (N_NODES + 63) / 64;             // 1563 (64 nodes/block)
    const int NB_PULL = N_NODES / 16;                  // 6250 (pull: 16 nodes/block)
    const int NB_P1 = (N_EDGES + P1_EPB - 1) / P1_EPB; // 782

    initcur_kernel<<<1, 1024, 0, stream>>>(gcursor);
    dropmask_kernel<<<(2 * NMASK) / 256, 256, 0, stream>>>(m1, m2,
                                                           dk1_0, dk1_1,
                                                           dk2_0, dk2_1);
    part1_kernel<<<NB_P1, 512, 0, stream>>>(src, dst, gcursor, buf);
    part2_kernel<<<NBKT, 512, 0, stream>>>(gcursor, buf, nodeinfo, dinv);
    ln_w1_kernel<<<NB_LN, 256, 0, stream>>>(x, gamma, beta, W1, dinv, g1h);
    pull1_kernel<<<NB_PULL, 256, 0, stream>>>(nodeinfo, buf, g1h,
                                              dinv, b1, W2, m1, g2h);
    pull2_kernel<<<NB_PULL, 256, 0, stream>>>(nodeinfo, buf, g2h,
                                              dinv, b2, m2, out);
}